// Round 4
// baseline (100.689 us; speedup 1.0000x reference)
//
#include <hip/hip_runtime.h>
#include <hip/hip_bf16.h>
#include <math.h>

#define D_MODEL 1024
#define INNER 2048
#define THREE_INNER 6144
#define D_STATE 64
#define LSEQ 1024
#define LN_EPS 1e-5f
#define SKTAPS 32

typedef __attribute__((ext_vector_type(4))) float f32x4;
typedef __attribute__((ext_vector_type(8))) short bf16x8;
typedef __attribute__((ext_vector_type(8))) unsigned short u16x8;

__device__ __forceinline__ float sigm(float x) { return 1.f / (1.f + __expf(-x)); }

__device__ __forceinline__ unsigned short f2bf(float f) {
    unsigned int u = __float_as_uint(f);
    unsigned int r = (u + 0x7FFF + ((u >> 16) & 1)) >> 16;
    return (unsigned short)r;
}
__device__ __forceinline__ float bf2f(unsigned short s) {
    return __uint_as_float(((unsigned int)s) << 16);
}

__device__ __forceinline__ void gload_lds16(const void* gsrc, void* ldst) {
    __builtin_amdgcn_global_load_lds(
        (const __attribute__((address_space(1))) void*)gsrc,
        (__attribute__((address_space(3))) void*)ldst,
        16, 0, 0);
}

// ---------------- LayerNorm -> bf16 h ----------------
__global__ __launch_bounds__(256) void ln_kernel(const float* __restrict__ x,
    const float* __restrict__ gamma, const float* __restrict__ beta,
    unsigned short* __restrict__ h) {
    int row = blockIdx.x;
    int tid = threadIdx.x;
    const float4 v = ((const float4*)(x + (size_t)row * D_MODEL))[tid];
    float sum = v.x + v.y + v.z + v.w;
    float sq  = v.x*v.x + v.y*v.y + v.z*v.z + v.w*v.w;
    #pragma unroll
    for (int off = 1; off < 64; off <<= 1) {
        sum += __shfl_xor(sum, off);
        sq  += __shfl_xor(sq,  off);
    }
    __shared__ float ssum[4], ssq[4];
    int wave = tid >> 6, lane = tid & 63;
    if (lane == 0) { ssum[wave] = sum; ssq[wave] = sq; }
    __syncthreads();
    sum = ssum[0] + ssum[1] + ssum[2] + ssum[3];
    sq  = ssq[0]  + ssq[1]  + ssq[2]  + ssq[3];
    float mu  = sum * (1.f / D_MODEL);
    float var = sq  * (1.f / D_MODEL) - mu * mu;
    float rstd = rsqrtf(var + LN_EPS);
    const float4 gv = ((const float4*)gamma)[tid];
    const float4 bv = ((const float4*)beta)[tid];
    ushort4 o;
    o.x = f2bf((v.x - mu) * rstd * gv.x + bv.x);
    o.y = f2bf((v.y - mu) * rstd * gv.y + bv.y);
    o.z = f2bf((v.z - mu) * rstd * gv.z + bv.z);
    o.w = f2bf((v.w - mu) * rstd * gv.w + bv.w);
    ((ushort4*)(h + (size_t)row * D_MODEL))[tid] = o;
}

// ---------------- transpose + cast: W fp32 [K][N] -> Wt bf16 [N][K] ----------------
__global__ __launch_bounds__(256) void transpose_cast_kernel(
    const float* __restrict__ W, unsigned short* __restrict__ Wt, int K, int N) {
    __shared__ float tile[64][65];
    int k0 = blockIdx.y * 64, n0 = blockIdx.x * 64;
    int r = threadIdx.x >> 2;      // 0..63
    int seg = threadIdx.x & 3;     // 16 elements each
    const float* src = W + (size_t)(k0 + r) * N + n0 + seg * 16;
    #pragma unroll
    for (int i = 0; i < 4; ++i) {
        float4 v = *(const float4*)(src + i * 4);
        tile[r][seg * 16 + i * 4 + 0] = v.x;
        tile[r][seg * 16 + i * 4 + 1] = v.y;
        tile[r][seg * 16 + i * 4 + 2] = v.z;
        tile[r][seg * 16 + i * 4 + 3] = v.w;
    }
    __syncthreads();
    int n = r, ks = seg;
    unsigned short pack[16];
    #pragma unroll
    for (int j = 0; j < 16; ++j) pack[j] = f2bf(tile[ks * 16 + j][n]);
    unsigned short* dst = Wt + (size_t)(n0 + n) * K + k0 + ks * 16;
    *(u16x8*)dst       = *(u16x8*)&pack[0];
    *(u16x8*)(dst + 8) = *(u16x8*)&pack[8];
}

// ---------------- bf16 MFMA GEMM, 2-phase double-buffered ----------------
// C = A(bf16 [M][K]) @ Bt^T (bf16 [N][K]) + bias (+resid)
template<int BM, int BN, bool OUT_BF16>
__global__ __launch_bounds__(256) void gemm_bt_kernel(
    const unsigned short* __restrict__ A,
    const unsigned short* __restrict__ Bt,
    const float* __restrict__ bias,
    const float* __restrict__ resid,
    void* __restrict__ Cv,
    int M, int N, int K) {
    constexpr int BK = 64;
    constexpr int FM = BM / 32;
    constexpr int FN = BN / 32;
    __shared__ __align__(16) unsigned short As[2][BM * BK];
    __shared__ __align__(16) unsigned short Bs[2][BN * BK];
    const int t = threadIdx.x;
    const int lane = t & 63;
    const int wave = t >> 6;
    const int wm = wave >> 1, wn = wave & 1;   // 2x2 wave grid, wave tile BM/2 x BN/2
    const int m0 = blockIdx.y * BM;
    const int n0 = blockIdx.x * BN;
    f32x4 acc[FM][FN] = {};

    const int srow = t >> 3;    // 0..31
    const int schunk = t & 7;   // 16B chunk within 64-elem row

    auto stage = [&](int buf, int k0) {
        #pragma unroll
        for (int i = 0; i < BM / 32; ++i) {
            int r = i * 32 + srow;
            int js = schunk ^ (r & 7);
            gload_lds16(A + (size_t)(m0 + r) * K + k0 + js * 8,
                        ((char*)As[buf]) + i * 4096 + wave * 1024);
        }
        #pragma unroll
        for (int i = 0; i < BN / 32; ++i) {
            int r = i * 32 + srow;
            int js = schunk ^ (r & 7);
            gload_lds16(Bt + (size_t)(n0 + r) * K + k0 + js * 8,
                        ((char*)Bs[buf]) + i * 4096 + wave * 1024);
        }
    };

    auto compute = [&](int buf) {
        #pragma unroll
        for (int kt = 0; kt < 2; ++kt) {
            bf16x8 af[FM], bfr[FN];
            #pragma unroll
            for (int i = 0; i < FM; ++i) {
                int row = wm * (BM / 2) + i * 16 + (lane & 15);
                int chunk = (kt * 4 + (lane >> 4)) ^ (row & 7);
                af[i] = *(const bf16x8*)(((const char*)As[buf]) + row * 128 + chunk * 16);
            }
            #pragma unroll
            for (int j = 0; j < FN; ++j) {
                int row = wn * (BN / 2) + j * 16 + (lane & 15);
                int chunk = (kt * 4 + (lane >> 4)) ^ (row & 7);
                bfr[j] = *(const bf16x8*)(((const char*)Bs[buf]) + row * 128 + chunk * 16);
            }
            #pragma unroll
            for (int i = 0; i < FM; ++i)
                #pragma unroll
                for (int j = 0; j < FN; ++j)
                    acc[i][j] = __builtin_amdgcn_mfma_f32_16x16x32_bf16(
                        af[i], bfr[j], acc[i][j], 0, 0, 0);
        }
    };

    stage(0, 0);
    __syncthreads();
    int cur = 0;
    const int NT = K / BK;
    for (int tt = 0; tt + 1 < NT; ++tt) {
        stage(cur ^ 1, (tt + 1) * BK);   // prefetch next tile (overlaps compute)
        compute(cur);
        __syncthreads();                 // drains vmcnt (mostly covered) + barrier
        cur ^= 1;
    }
    compute(cur);

    #pragma unroll
    for (int i = 0; i < FM; ++i) {
        #pragma unroll
        for (int j = 0; j < FN; ++j) {
            int col = n0 + wn * (BN / 2) + j * 16 + (lane & 15);
            float bv = bias[col];
            #pragma unroll
            for (int r = 0; r < 4; ++r) {
                int row = m0 + wm * (BM / 2) + i * 16 + (lane >> 4) * 4 + r;
                float val = acc[i][j][r] + bv;
                if (OUT_BF16) {
                    ((unsigned short*)Cv)[(size_t)row * N + col] = f2bf(val);
                } else {
                    if (resid) val += resid[(size_t)row * N + col];
                    ((float*)Cv)[(size_t)row * N + col] = val;
                }
            }
        }
    }
}

// ---------------- precompute tap kernels: kbuf[d][c] = sum_n C*B*decay^d (+D at d=0)
__global__ __launch_bounds__(256) void kprec_kernel(
    const float* __restrict__ A_log, const float* __restrict__ Bp,
    const float* __restrict__ Cp, const float* __restrict__ Dp,
    float* __restrict__ kbuf) {
    int lane = threadIdx.x & 63;                  // state n
    int c = blockIdx.x * 4 + (threadIdx.x >> 6);  // channel
    float e1 = __expf(-__expf(A_log[c * 64 + lane]));   // per-state decay
    float wgt = Bp[c * 64 + lane] * Cp[c * 64 + lane];  // bc * e1^0
    float d0 = Dp[c];
    #pragma unroll
    for (int d = 0; d < SKTAPS; ++d) {
        float s = wgt;
        s += __shfl_xor(s, 32);
        s += __shfl_xor(s, 16);
        s += __shfl_xor(s, 8);
        s += __shfl_xor(s, 4);
        s += __shfl_xor(s, 2);
        s += __shfl_xor(s, 1);
        if (lane == 0) kbuf[(size_t)d * INNER + c] = s + (d == 0 ? d0 : 0.f);
        wgt *= e1;
    }
}

// ---------------- fused: silu(conv3(u)) -> 32-tap causal conv -> gate ----------------
__global__ __launch_bounds__(256) void ssm_fused_kernel(
    const unsigned short* __restrict__ uvg,   // bf16 [L][3*INNER]
    const float* __restrict__ conv_w, const float* __restrict__ conv_b,
    const float* __restrict__ kbuf,           // [32][INNER]
    unsigned short* __restrict__ ybf) {
    int lane = threadIdx.x & 63;
    int wave = threadIdx.x >> 6;
    int c = (blockIdx.x & 31) * 64 + lane;
    int t0 = (blockIdx.x >> 5) * 64 + wave * 16;
    const unsigned short* up = uvg + c;
    const float* kc = kbuf + c;
    float cw0 = conv_w[c * 3 + 0];
    float cw1 = conv_w[c * 3 + 1];
    float cw2 = conv_w[c * 3 + 2];
    float cb  = conv_b[c];

    auto raw = [&](int tt) -> float {
        return (tt >= 0 && tt < LSEQ) ? bf2f(up[(size_t)tt * THREE_INNER]) : 0.f;
    };
    auto clean = [&](float rm1, float r0, float rp1) -> float {
        float a = fmaf(rp1, cw2, fmaf(r0, cw1, fmaf(rm1, cw0, cb)));
        return a * sigm(a);
    };

    // cleaned u for t0..t0+15 (ascending, sliding raw triple)
    float w[16];
    {
        float rm1 = raw(t0 - 1), r0 = raw(t0);
        #pragma unroll
        for (int j = 0; j < 16; ++j) {
            float rp1 = raw(t0 + j + 1);
            w[j] = clean(rm1, r0, rp1);
            rm1 = r0; r0 = rp1;
        }
    }
    float acc[16] = {};
    // descending raw triple for older cleaned values
    float q0 = raw(t0), q1 = raw(t0 - 1);
    #pragma unroll
    for (int d = 0; d < SKTAPS; ++d) {
        float kd = kc[(size_t)d * INNER];
        #pragma unroll
        for (int j = 0; j < 16; ++j) acc[j] = fmaf(kd, w[j], acc[j]);
        if (d < SKTAPS - 1) {
            float q2 = raw(t0 - 2 - d);
            float nc = (t0 - 1 - d >= 0) ? clean(q2, q1, q0) : 0.f;
            #pragma unroll
            for (int j = 15; j > 0; --j) w[j] = w[j - 1];
            w[0] = nc;
            q0 = q1; q1 = q2;
        }
    }
    #pragma unroll
    for (int j = 0; j < 16; ++j) {
        size_t tt = (size_t)(t0 + j);
        float v = bf2f(uvg[tt * THREE_INNER + INNER + c]);
        float g = bf2f(uvg[tt * THREE_INNER + 2 * INNER + c]);
        float o = acc[j] * sigm(g) + v * sigm(v);
        ybf[tt * INNER + c] = f2bf(o);
    }
}

extern "C" void kernel_launch(void* const* d_in, const int* in_sizes, int n_in,
                              void* d_out, int out_size, void* d_ws, size_t ws_size,
                              hipStream_t stream) {
    const float* x       = (const float*)d_in[0];
    const float* gamma   = (const float*)d_in[1];
    const float* beta    = (const float*)d_in[2];
    const float* in_w    = (const float*)d_in[3];
    const float* in_b    = (const float*)d_in[4];
    const float* conv_w  = (const float*)d_in[5];
    const float* conv_b  = (const float*)d_in[6];
    const float* A_log   = (const float*)d_in[7];
    const float* B_p     = (const float*)d_in[8];
    const float* C_p     = (const float*)d_in[9];
    const float* D_p     = (const float*)d_in[10];
    const float* out_w   = (const float*)d_in[11];
    const float* out_b   = (const float*)d_in[12];
    float* out = (float*)d_out;

    char* ws = (char*)d_ws;
    unsigned short* h      = (unsigned short*)ws;  ws += (size_t)LSEQ * D_MODEL * 2;
    unsigned short* uvg    = (unsigned short*)ws;  ws += (size_t)LSEQ * THREE_INNER * 2;
    unsigned short* ybf    = (unsigned short*)ws;  ws += (size_t)LSEQ * INNER * 2;
    float*          kbuf   = (float*)ws;           ws += (size_t)SKTAPS * INNER * 4;
    unsigned short* in_wt  = (unsigned short*)ws;  ws += (size_t)THREE_INNER * D_MODEL * 2;
    unsigned short* out_wt = (unsigned short*)ws;  ws += (size_t)D_MODEL * INNER * 2;

    {
        dim3 g(THREE_INNER / 64, D_MODEL / 64);
        transpose_cast_kernel<<<g, 256, 0, stream>>>(in_w, in_wt, D_MODEL, THREE_INNER);
    }
    {
        dim3 g(D_MODEL / 64, INNER / 64);
        transpose_cast_kernel<<<g, 256, 0, stream>>>(out_w, out_wt, INNER, D_MODEL);
    }

    ln_kernel<<<LSEQ, 256, 0, stream>>>(x, gamma, beta, h);

    kprec_kernel<<<INNER / 4, 256, 0, stream>>>(A_log, B_p, C_p, D_p, kbuf);

    {   // GEMM1: (1024x1024) @ (1024x6144) -> uvg (bf16)
        dim3 g(THREE_INNER / 128, LSEQ / 128);
        gemm_bt_kernel<128, 128, true><<<g, 256, 0, stream>>>(h, in_wt, in_b, nullptr, uvg,
                                                              LSEQ, THREE_INNER, D_MODEL);
    }

    ssm_fused_kernel<<<(LSEQ / 64) * 32, 256, 0, stream>>>(uvg, conv_w, conv_b, kbuf, ybf);

    {   // GEMM2: (1024x2048) @ (2048x1024) + out_b + x -> out (fp32)
        dim3 g(D_MODEL / 64, LSEQ / 64);
        gemm_bt_kernel<64, 64, false><<<g, 256, 0, stream>>>(ybf, out_wt, out_b, x, out,
                                                             LSEQ, D_MODEL, INNER);
    }
}

// Round 5
// 90.598 us; speedup vs baseline: 1.1114x; 1.1114x over previous
//
#include <hip/hip_runtime.h>
#include <hip/hip_bf16.h>
#include <math.h>

#define D_MODEL 1024
#define INNER 2048
#define THREE_INNER 6144
#define D_STATE 64
#define LSEQ 1024
#define LN_EPS 1e-5f
#define SKTAPS 32
#define KSPLIT 4

typedef __attribute__((ext_vector_type(4))) float f32x4;
typedef __attribute__((ext_vector_type(8))) short bf16x8;
typedef __attribute__((ext_vector_type(8))) unsigned short u16x8;

__device__ __forceinline__ float sigm(float x) { return 1.f / (1.f + __expf(-x)); }

__device__ __forceinline__ unsigned short f2bf(float f) {
    unsigned int u = __float_as_uint(f);
    unsigned int r = (u + 0x7FFF + ((u >> 16) & 1)) >> 16;
    return (unsigned short)r;
}
__device__ __forceinline__ float bf2f(unsigned short s) {
    return __uint_as_float(((unsigned int)s) << 16);
}

__device__ __forceinline__ void gload_lds16(const void* gsrc, void* ldst) {
    __builtin_amdgcn_global_load_lds(
        (const __attribute__((address_space(1))) void*)gsrc,
        (__attribute__((address_space(3))) void*)ldst,
        16, 0, 0);
}

// ---------------- LayerNorm -> bf16 h ----------------
__global__ __launch_bounds__(256) void ln_kernel(const float* __restrict__ x,
    const float* __restrict__ gamma, const float* __restrict__ beta,
    unsigned short* __restrict__ h) {
    int row = blockIdx.x;
    int tid = threadIdx.x;
    const float4 v = ((const float4*)(x + (size_t)row * D_MODEL))[tid];
    float sum = v.x + v.y + v.z + v.w;
    float sq  = v.x*v.x + v.y*v.y + v.z*v.z + v.w*v.w;
    #pragma unroll
    for (int off = 1; off < 64; off <<= 1) {
        sum += __shfl_xor(sum, off);
        sq  += __shfl_xor(sq,  off);
    }
    __shared__ float ssum[4], ssq[4];
    int wave = tid >> 6, lane = tid & 63;
    if (lane == 0) { ssum[wave] = sum; ssq[wave] = sq; }
    __syncthreads();
    sum = ssum[0] + ssum[1] + ssum[2] + ssum[3];
    sq  = ssq[0]  + ssq[1]  + ssq[2]  + ssq[3];
    float mu  = sum * (1.f / D_MODEL);
    float var = sq  * (1.f / D_MODEL) - mu * mu;
    float rstd = rsqrtf(var + LN_EPS);
    const float4 gv = ((const float4*)gamma)[tid];
    const float4 bv = ((const float4*)beta)[tid];
    ushort4 o;
    o.x = f2bf((v.x - mu) * rstd * gv.x + bv.x);
    o.y = f2bf((v.y - mu) * rstd * gv.y + bv.y);
    o.z = f2bf((v.z - mu) * rstd * gv.z + bv.z);
    o.w = f2bf((v.w - mu) * rstd * gv.w + bv.w);
    ((ushort4*)(h + (size_t)row * D_MODEL))[tid] = o;
}

// ---------------- transpose + cast: W fp32 [K][N] -> Wt bf16 [N][K] ----------------
__global__ __launch_bounds__(256) void transpose_cast_kernel(
    const float* __restrict__ W, unsigned short* __restrict__ Wt, int K, int N) {
    __shared__ float tile[64][65];
    int k0 = blockIdx.y * 64, n0 = blockIdx.x * 64;
    int r = threadIdx.x >> 2;      // 0..63
    int seg = threadIdx.x & 3;     // 16 elements each
    const float* src = W + (size_t)(k0 + r) * N + n0 + seg * 16;
    #pragma unroll
    for (int i = 0; i < 4; ++i) {
        float4 v = *(const float4*)(src + i * 4);
        tile[r][seg * 16 + i * 4 + 0] = v.x;
        tile[r][seg * 16 + i * 4 + 1] = v.y;
        tile[r][seg * 16 + i * 4 + 2] = v.z;
        tile[r][seg * 16 + i * 4 + 3] = v.w;
    }
    __syncthreads();
    int n = r, ks = seg;
    unsigned short pack[16];
    #pragma unroll
    for (int j = 0; j < 16; ++j) pack[j] = f2bf(tile[ks * 16 + j][n]);
    unsigned short* dst = Wt + (size_t)(n0 + n) * K + k0 + ks * 16;
    *(u16x8*)dst       = *(u16x8*)&pack[0];
    *(u16x8*)(dst + 8) = *(u16x8*)&pack[8];
}

// ---------------- bf16 MFMA GEMM, single-buffered (R2-proven structure) ----------
// C = A(bf16 [M][K]) @ Bt^T (bf16 [N][K]) + bias
template<int BM, int BN, bool OUT_BF16>
__global__ __launch_bounds__(256) void gemm_bt_kernel(
    const unsigned short* __restrict__ A,
    const unsigned short* __restrict__ Bt,
    const float* __restrict__ bias,
    void* __restrict__ Cv,
    int M, int N, int K) {
    constexpr int BK = 64;
    constexpr int FM = BM / 32;
    constexpr int FN = BN / 32;
    __shared__ __align__(16) unsigned short As[BM * BK];
    __shared__ __align__(16) unsigned short Bs[BN * BK];
    const int t = threadIdx.x;
    const int lane = t & 63;
    const int wave = t >> 6;
    const int wm = wave >> 1, wn = wave & 1;
    const int m0 = blockIdx.y * BM;
    const int n0 = blockIdx.x * BN;
    f32x4 acc[FM][FN] = {};

    const int srow = t >> 3;
    const int schunk = t & 7;

    for (int k0 = 0; k0 < K; k0 += BK) {
        #pragma unroll
        for (int i = 0; i < BM / 32; ++i) {
            int r = i * 32 + srow;
            int js = schunk ^ (r & 7);
            gload_lds16(A + (size_t)(m0 + r) * K + k0 + js * 8,
                        ((char*)As) + i * 4096 + wave * 1024);
        }
        #pragma unroll
        for (int i = 0; i < BN / 32; ++i) {
            int r = i * 32 + srow;
            int js = schunk ^ (r & 7);
            gload_lds16(Bt + (size_t)(n0 + r) * K + k0 + js * 8,
                        ((char*)Bs) + i * 4096 + wave * 1024);
        }
        __syncthreads();
        #pragma unroll
        for (int kt = 0; kt < 2; ++kt) {
            bf16x8 af[FM], bfr[FN];
            #pragma unroll
            for (int i = 0; i < FM; ++i) {
                int row = wm * (BM / 2) + i * 16 + (lane & 15);
                int chunk = (kt * 4 + (lane >> 4)) ^ (row & 7);
                af[i] = *(const bf16x8*)(((const char*)As) + row * 128 + chunk * 16);
            }
            #pragma unroll
            for (int j = 0; j < FN; ++j) {
                int row = wn * (BN / 2) + j * 16 + (lane & 15);
                int chunk = (kt * 4 + (lane >> 4)) ^ (row & 7);
                bfr[j] = *(const bf16x8*)(((const char*)Bs) + row * 128 + chunk * 16);
            }
            #pragma unroll
            for (int i = 0; i < FM; ++i)
                #pragma unroll
                for (int j = 0; j < FN; ++j)
                    acc[i][j] = __builtin_amdgcn_mfma_f32_16x16x32_bf16(
                        af[i], bfr[j], acc[i][j], 0, 0, 0);
        }
        __syncthreads();
    }

    #pragma unroll
    for (int i = 0; i < FM; ++i) {
        #pragma unroll
        for (int j = 0; j < FN; ++j) {
            int col = n0 + wn * (BN / 2) + j * 16 + (lane & 15);
            float bv = bias[col];
            #pragma unroll
            for (int r = 0; r < 4; ++r) {
                int row = m0 + wm * (BM / 2) + i * 16 + (lane >> 4) * 4 + r;
                float val = acc[i][j][r] + bv;
                if (OUT_BF16) {
                    ((unsigned short*)Cv)[(size_t)row * N + col] = f2bf(val);
                } else {
                    ((float*)Cv)[(size_t)row * N + col] = val;
                }
            }
        }
    }
}

// ---------------- split-K GEMM2: partial[kz] = A[:, kz*KS:...] @ Bt^T, fp32 -------
__global__ __launch_bounds__(256) void gemm_bt_splitk_kernel(
    const unsigned short* __restrict__ A,
    const unsigned short* __restrict__ Bt,
    float* __restrict__ part,
    int M, int N, int K) {
    constexpr int BM = 64, BN = 64, BK = 64;
    constexpr int FM = 2, FN = 2;
    __shared__ __align__(16) unsigned short As[BM * BK];
    __shared__ __align__(16) unsigned short Bs[BN * BK];
    const int t = threadIdx.x;
    const int lane = t & 63;
    const int wave = t >> 6;
    const int wm = wave >> 1, wn = wave & 1;
    const int m0 = blockIdx.y * BM;
    const int n0 = blockIdx.x * BN;
    const int kz = blockIdx.z;
    const int klen = K / KSPLIT;
    const int kbase = kz * klen;
    f32x4 acc[FM][FN] = {};

    const int srow = t >> 3;
    const int schunk = t & 7;

    for (int k0 = kbase; k0 < kbase + klen; k0 += BK) {
        #pragma unroll
        for (int i = 0; i < BM / 32; ++i) {
            int r = i * 32 + srow;
            int js = schunk ^ (r & 7);
            gload_lds16(A + (size_t)(m0 + r) * K + k0 + js * 8,
                        ((char*)As) + i * 4096 + wave * 1024);
        }
        #pragma unroll
        for (int i = 0; i < BN / 32; ++i) {
            int r = i * 32 + srow;
            int js = schunk ^ (r & 7);
            gload_lds16(Bt + (size_t)(n0 + r) * K + k0 + js * 8,
                        ((char*)Bs) + i * 4096 + wave * 1024);
        }
        __syncthreads();
        #pragma unroll
        for (int kt = 0; kt < 2; ++kt) {
            bf16x8 af[FM], bfr[FN];
            #pragma unroll
            for (int i = 0; i < FM; ++i) {
                int row = wm * 32 + i * 16 + (lane & 15);
                int chunk = (kt * 4 + (lane >> 4)) ^ (row & 7);
                af[i] = *(const bf16x8*)(((const char*)As) + row * 128 + chunk * 16);
            }
            #pragma unroll
            for (int j = 0; j < FN; ++j) {
                int row = wn * 32 + j * 16 + (lane & 15);
                int chunk = (kt * 4 + (lane >> 4)) ^ (row & 7);
                bfr[j] = *(const bf16x8*)(((const char*)Bs) + row * 128 + chunk * 16);
            }
            #pragma unroll
            for (int i = 0; i < FM; ++i)
                #pragma unroll
                for (int j = 0; j < FN; ++j)
                    acc[i][j] = __builtin_amdgcn_mfma_f32_16x16x32_bf16(
                        af[i], bfr[j], acc[i][j], 0, 0, 0);
        }
        __syncthreads();
    }

    float* dst = part + (size_t)kz * M * N;
    #pragma unroll
    for (int i = 0; i < FM; ++i)
        #pragma unroll
        for (int j = 0; j < FN; ++j) {
            int col = n0 + wn * 32 + j * 16 + (lane & 15);
            #pragma unroll
            for (int r = 0; r < 4; ++r) {
                int row = m0 + wm * 32 + i * 16 + (lane >> 4) * 4 + r;
                dst[(size_t)row * N + col] = acc[i][j][r];
            }
        }
}

// ---------------- reduce partials + bias + residual ----------------
__global__ __launch_bounds__(256) void splitk_reduce_kernel(
    const float* __restrict__ part, const float* __restrict__ bias,
    const float* __restrict__ resid, float* __restrict__ out) {
    int idx = blockIdx.x * 256 + threadIdx.x;      // float4 index over M*N/4
    const size_t MN = (size_t)LSEQ * D_MODEL;
    f32x4 a = ((const f32x4*)part)[idx];
    #pragma unroll
    for (int z = 1; z < KSPLIT; ++z) {
        f32x4 p = ((const f32x4*)(part + z * MN))[idx];
        a.x += p.x; a.y += p.y; a.z += p.z; a.w += p.w;
    }
    int col4 = idx & (D_MODEL / 4 - 1);
    f32x4 bv = ((const f32x4*)bias)[col4];
    f32x4 rv = ((const f32x4*)resid)[idx];
    a.x += bv.x + rv.x; a.y += bv.y + rv.y; a.z += bv.z + rv.z; a.w += bv.w + rv.w;
    ((f32x4*)out)[idx] = a;
}

// ---------------- precompute tap kernels ----------------
__global__ __launch_bounds__(256) void kprec_kernel(
    const float* __restrict__ A_log, const float* __restrict__ Bp,
    const float* __restrict__ Cp, const float* __restrict__ Dp,
    float* __restrict__ kbuf) {
    int lane = threadIdx.x & 63;
    int c = blockIdx.x * 4 + (threadIdx.x >> 6);
    float e1 = __expf(-__expf(A_log[c * 64 + lane]));
    float wgt = Bp[c * 64 + lane] * Cp[c * 64 + lane];
    float d0 = Dp[c];
    #pragma unroll
    for (int d = 0; d < SKTAPS; ++d) {
        float s = wgt;
        s += __shfl_xor(s, 32);
        s += __shfl_xor(s, 16);
        s += __shfl_xor(s, 8);
        s += __shfl_xor(s, 4);
        s += __shfl_xor(s, 2);
        s += __shfl_xor(s, 1);
        if (lane == 0) kbuf[(size_t)d * INNER + c] = s + (d == 0 ? d0 : 0.f);
        wgt *= e1;
    }
}

// ---------------- fused: silu(conv3(u)) -> 32-tap causal conv -> gate ----------------
__global__ __launch_bounds__(256) void ssm_fused_kernel(
    const unsigned short* __restrict__ uvg,
    const float* __restrict__ conv_w, const float* __restrict__ conv_b,
    const float* __restrict__ kbuf,
    unsigned short* __restrict__ ybf) {
    int lane = threadIdx.x & 63;
    int wave = threadIdx.x >> 6;
    int c = (blockIdx.x & 31) * 64 + lane;
    int t0 = (blockIdx.x >> 5) * 64 + wave * 16;
    const unsigned short* up = uvg + c;
    const float* kc = kbuf + c;
    float cw0 = conv_w[c * 3 + 0];
    float cw1 = conv_w[c * 3 + 1];
    float cw2 = conv_w[c * 3 + 2];
    float cb  = conv_b[c];

    auto raw = [&](int tt) -> float {
        return (tt >= 0 && tt < LSEQ) ? bf2f(up[(size_t)tt * THREE_INNER]) : 0.f;
    };
    auto clean = [&](float rm1, float r0, float rp1) -> float {
        float a = fmaf(rp1, cw2, fmaf(r0, cw1, fmaf(rm1, cw0, cb)));
        return a * sigm(a);
    };

    float w[16];
    {
        float rm1 = raw(t0 - 1), r0 = raw(t0);
        #pragma unroll
        for (int j = 0; j < 16; ++j) {
            float rp1 = raw(t0 + j + 1);
            w[j] = clean(rm1, r0, rp1);
            rm1 = r0; r0 = rp1;
        }
    }
    float acc[16] = {};
    float q0 = raw(t0), q1 = raw(t0 - 1);
    #pragma unroll
    for (int d = 0; d < SKTAPS; ++d) {
        float kd = kc[(size_t)d * INNER];
        #pragma unroll
        for (int j = 0; j < 16; ++j) acc[j] = fmaf(kd, w[j], acc[j]);
        if (d < SKTAPS - 1) {
            float q2 = raw(t0 - 2 - d);
            float nc = (t0 - 1 - d >= 0) ? clean(q2, q1, q0) : 0.f;
            #pragma unroll
            for (int j = 15; j > 0; --j) w[j] = w[j - 1];
            w[0] = nc;
            q0 = q1; q1 = q2;
        }
    }
    #pragma unroll
    for (int j = 0; j < 16; ++j) {
        size_t tt = (size_t)(t0 + j);
        float v = bf2f(uvg[tt * THREE_INNER + INNER + c]);
        float g = bf2f(uvg[tt * THREE_INNER + 2 * INNER + c]);
        float o = acc[j] * sigm(g) + v * sigm(v);
        ybf[tt * INNER + c] = f2bf(o);
    }
}

extern "C" void kernel_launch(void* const* d_in, const int* in_sizes, int n_in,
                              void* d_out, int out_size, void* d_ws, size_t ws_size,
                              hipStream_t stream) {
    const float* x       = (const float*)d_in[0];
    const float* gamma   = (const float*)d_in[1];
    const float* beta    = (const float*)d_in[2];
    const float* in_w    = (const float*)d_in[3];
    const float* in_b    = (const float*)d_in[4];
    const float* conv_w  = (const float*)d_in[5];
    const float* conv_b  = (const float*)d_in[6];
    const float* A_log   = (const float*)d_in[7];
    const float* B_p     = (const float*)d_in[8];
    const float* C_p     = (const float*)d_in[9];
    const float* D_p     = (const float*)d_in[10];
    const float* out_w   = (const float*)d_in[11];
    const float* out_b   = (const float*)d_in[12];
    float* out = (float*)d_out;

    char* ws = (char*)d_ws;
    unsigned short* h      = (unsigned short*)ws;  ws += (size_t)LSEQ * D_MODEL * 2;
    unsigned short* uvg    = (unsigned short*)ws;  ws += (size_t)LSEQ * THREE_INNER * 2;
    unsigned short* ybf    = (unsigned short*)ws;  ws += (size_t)LSEQ * INNER * 2;
    float*          kbuf   = (float*)ws;           ws += (size_t)SKTAPS * INNER * 4;
    unsigned short* in_wt  = (unsigned short*)ws;  ws += (size_t)THREE_INNER * D_MODEL * 2;
    unsigned short* out_wt = (unsigned short*)ws;  ws += (size_t)D_MODEL * INNER * 2;
    float*          part   = (float*)ws;           ws += (size_t)KSPLIT * LSEQ * D_MODEL * 4;

    {
        dim3 g(THREE_INNER / 64, D_MODEL / 64);
        transpose_cast_kernel<<<g, 256, 0, stream>>>(in_w, in_wt, D_MODEL, THREE_INNER);
    }
    {
        dim3 g(D_MODEL / 64, INNER / 64);
        transpose_cast_kernel<<<g, 256, 0, stream>>>(out_w, out_wt, INNER, D_MODEL);
    }

    ln_kernel<<<LSEQ, 256, 0, stream>>>(x, gamma, beta, h);

    kprec_kernel<<<INNER / 4, 256, 0, stream>>>(A_log, B_p, C_p, D_p, kbuf);

    {   // GEMM1: (1024x1024) @ (1024x6144) -> uvg (bf16), R2-proven 64x128 tile
        dim3 g(THREE_INNER / 128, LSEQ / 64);
        gemm_bt_kernel<64, 128, true><<<g, 256, 0, stream>>>(h, in_wt, in_b, uvg,
                                                             LSEQ, THREE_INNER, D_MODEL);
    }

    ssm_fused_kernel<<<(LSEQ / 64) * 32, 256, 0, stream>>>(uvg, conv_w, conv_b, kbuf, ybf);

    {   // GEMM2 split-K: (1024x2048) @ (2048x1024) -> 4 partials
        dim3 g(D_MODEL / 64, LSEQ / 64, KSPLIT);
        gemm_bt_splitk_kernel<<<g, 256, 0, stream>>>(ybf, out_wt, part,
                                                     LSEQ, D_MODEL, INNER);
    }
    splitk_reduce_kernel<<<(LSEQ * D_MODEL / 4) / 256, 256, 0, stream>>>(
        part, out_b, x, out);
}

// Round 6
// 88.317 us; speedup vs baseline: 1.1401x; 1.0258x over previous
//
#include <hip/hip_runtime.h>
#include <hip/hip_bf16.h>
#include <math.h>

#define D_MODEL 1024
#define INNER 2048
#define THREE_INNER 6144
#define D_STATE 64
#define LSEQ 1024
#define LN_EPS 1e-5f
#define SKTAPS 32
#define KSPLIT 4

typedef __attribute__((ext_vector_type(4))) float f32x4;
typedef __attribute__((ext_vector_type(8))) short bf16x8;
typedef __attribute__((ext_vector_type(8))) unsigned short u16x8;

__device__ __forceinline__ float sigm(float x) { return 1.f / (1.f + __expf(-x)); }

__device__ __forceinline__ unsigned short f2bf(float f) {
    unsigned int u = __float_as_uint(f);
    unsigned int r = (u + 0x7FFF + ((u >> 16) & 1)) >> 16;
    return (unsigned short)r;
}
__device__ __forceinline__ float bf2f(unsigned short s) {
    return __uint_as_float(((unsigned int)s) << 16);
}

__device__ __forceinline__ void gload_lds16(const void* gsrc, void* ldst) {
    __builtin_amdgcn_global_load_lds(
        (const __attribute__((address_space(1))) void*)gsrc,
        (__attribute__((address_space(3))) void*)ldst,
        16, 0, 0);
}

// ================= merged preprocessing kernel =================
// blocks [0,1536): transpose+cast in_w  (K=1024 -> N=6144), 64x64 tiles (96 x 16)
// blocks [1536,2048): transpose+cast out_w (K=2048 -> N=1024), tiles (16 x 32)
// blocks [2048,3072): layernorm rows
// blocks [3072,3584): kprec, 4 channels per block
__device__ __forceinline__ void transpose_tile(
    const float* __restrict__ W, unsigned short* __restrict__ Wt,
    int K, int N, int k0, int n0) {
    __shared__ float tile[64][65];
    int r = threadIdx.x >> 2;      // 0..63
    int seg = threadIdx.x & 3;     // 16 elements each
    const float* src = W + (size_t)(k0 + r) * N + n0 + seg * 16;
    #pragma unroll
    for (int i = 0; i < 4; ++i) {
        float4 v = *(const float4*)(src + i * 4);
        tile[r][seg * 16 + i * 4 + 0] = v.x;
        tile[r][seg * 16 + i * 4 + 1] = v.y;
        tile[r][seg * 16 + i * 4 + 2] = v.z;
        tile[r][seg * 16 + i * 4 + 3] = v.w;
    }
    __syncthreads();
    int n = r, ks = seg;
    unsigned short pack[16];
    #pragma unroll
    for (int j = 0; j < 16; ++j) pack[j] = f2bf(tile[ks * 16 + j][n]);
    unsigned short* dst = Wt + (size_t)(n0 + n) * K + k0 + ks * 16;
    *(u16x8*)dst       = *(u16x8*)&pack[0];
    *(u16x8*)(dst + 8) = *(u16x8*)&pack[8];
}

__global__ __launch_bounds__(256) void prep_kernel(
    const float* __restrict__ in_w,  unsigned short* __restrict__ in_wt,
    const float* __restrict__ out_w, unsigned short* __restrict__ out_wt,
    const float* __restrict__ x, const float* __restrict__ gamma,
    const float* __restrict__ beta, unsigned short* __restrict__ h,
    const float* __restrict__ A_log, const float* __restrict__ Bp,
    const float* __restrict__ Cp, const float* __restrict__ Dp,
    float* __restrict__ kbuf) {
    int b = blockIdx.x;
    if (b < 1536) {
        // in_w: K=1024, N=6144; n-tiles = 96
        int bx = b % 96, by = b / 96;
        transpose_tile(in_w, in_wt, D_MODEL, THREE_INNER, by * 64, bx * 64);
        return;
    }
    if (b < 2048) {
        // out_w: K=2048, N=1024; n-tiles = 16
        int b2 = b - 1536;
        int bx = b2 % 16, by = b2 / 16;
        transpose_tile(out_w, out_wt, INNER, D_MODEL, by * 64, bx * 64);
        return;
    }
    if (b < 3072) {
        int row = b - 2048;
        int tid = threadIdx.x;
        const float4 v = ((const float4*)(x + (size_t)row * D_MODEL))[tid];
        float sum = v.x + v.y + v.z + v.w;
        float sq  = v.x*v.x + v.y*v.y + v.z*v.z + v.w*v.w;
        #pragma unroll
        for (int off = 1; off < 64; off <<= 1) {
            sum += __shfl_xor(sum, off);
            sq  += __shfl_xor(sq,  off);
        }
        __shared__ float ssum[4], ssq[4];
        int wave = tid >> 6, lane = tid & 63;
        if (lane == 0) { ssum[wave] = sum; ssq[wave] = sq; }
        __syncthreads();
        sum = ssum[0] + ssum[1] + ssum[2] + ssum[3];
        sq  = ssq[0]  + ssq[1]  + ssq[2]  + ssq[3];
        float mu  = sum * (1.f / D_MODEL);
        float var = sq  * (1.f / D_MODEL) - mu * mu;
        float rstd = rsqrtf(var + LN_EPS);
        const float4 gv = ((const float4*)gamma)[tid];
        const float4 bv = ((const float4*)beta)[tid];
        ushort4 o;
        o.x = f2bf((v.x - mu) * rstd * gv.x + bv.x);
        o.y = f2bf((v.y - mu) * rstd * gv.y + bv.y);
        o.z = f2bf((v.z - mu) * rstd * gv.z + bv.z);
        o.w = f2bf((v.w - mu) * rstd * gv.w + bv.w);
        ((ushort4*)(h + (size_t)row * D_MODEL))[tid] = o;
        return;
    }
    {
        int lane = threadIdx.x & 63;
        int c = (b - 3072) * 4 + (threadIdx.x >> 6);
        float e1 = __expf(-__expf(A_log[c * 64 + lane]));
        float wgt = Bp[c * 64 + lane] * Cp[c * 64 + lane];
        float d0 = Dp[c];
        #pragma unroll
        for (int d = 0; d < SKTAPS; ++d) {
            float s = wgt;
            s += __shfl_xor(s, 32);
            s += __shfl_xor(s, 16);
            s += __shfl_xor(s, 8);
            s += __shfl_xor(s, 4);
            s += __shfl_xor(s, 2);
            s += __shfl_xor(s, 1);
            if (lane == 0) kbuf[(size_t)d * INNER + c] = s + (d == 0 ? d0 : 0.f);
            wgt *= e1;
        }
    }
}

// ---------------- bf16 MFMA GEMM, single-buffered ----------------
// C = A(bf16 [M][K]) @ Bt^T (bf16 [N][K]) + bias; 2x2 waves, wave tile BM/2 x BN/2
template<int BM, int BN, bool OUT_BF16>
__global__ __launch_bounds__(256) void gemm_bt_kernel(
    const unsigned short* __restrict__ A,
    const unsigned short* __restrict__ Bt,
    const float* __restrict__ bias,
    void* __restrict__ Cv,
    int M, int N, int K) {
    constexpr int BK = 64;
    constexpr int FM = BM / 32;
    constexpr int FN = BN / 32;
    __shared__ __align__(16) unsigned short As[BM * BK];
    __shared__ __align__(16) unsigned short Bs[BN * BK];
    const int t = threadIdx.x;
    const int lane = t & 63;
    const int wave = t >> 6;
    const int wm = wave >> 1, wn = wave & 1;
    const int m0 = blockIdx.y * BM;
    const int n0 = blockIdx.x * BN;
    f32x4 acc[FM][FN] = {};

    const int srow = t >> 3;
    const int schunk = t & 7;

    for (int k0 = 0; k0 < K; k0 += BK) {
        #pragma unroll
        for (int i = 0; i < BM / 32; ++i) {
            int r = i * 32 + srow;
            int js = schunk ^ (r & 7);
            gload_lds16(A + (size_t)(m0 + r) * K + k0 + js * 8,
                        ((char*)As) + i * 4096 + wave * 1024);
        }
        #pragma unroll
        for (int i = 0; i < BN / 32; ++i) {
            int r = i * 32 + srow;
            int js = schunk ^ (r & 7);
            gload_lds16(Bt + (size_t)(n0 + r) * K + k0 + js * 8,
                        ((char*)Bs) + i * 4096 + wave * 1024);
        }
        __syncthreads();
        #pragma unroll
        for (int kt = 0; kt < 2; ++kt) {
            bf16x8 af[FM], bfr[FN];
            #pragma unroll
            for (int i = 0; i < FM; ++i) {
                int row = wm * (BM / 2) + i * 16 + (lane & 15);
                int chunk = (kt * 4 + (lane >> 4)) ^ (row & 7);
                af[i] = *(const bf16x8*)(((const char*)As) + row * 128 + chunk * 16);
            }
            #pragma unroll
            for (int j = 0; j < FN; ++j) {
                int row = wn * (BN / 2) + j * 16 + (lane & 15);
                int chunk = (kt * 4 + (lane >> 4)) ^ (row & 7);
                bfr[j] = *(const bf16x8*)(((const char*)Bs) + row * 128 + chunk * 16);
            }
            #pragma unroll
            for (int i = 0; i < FM; ++i)
                #pragma unroll
                for (int j = 0; j < FN; ++j)
                    acc[i][j] = __builtin_amdgcn_mfma_f32_16x16x32_bf16(
                        af[i], bfr[j], acc[i][j], 0, 0, 0);
        }
        __syncthreads();
    }

    #pragma unroll
    for (int i = 0; i < FM; ++i) {
        #pragma unroll
        for (int j = 0; j < FN; ++j) {
            int col = n0 + wn * (BN / 2) + j * 16 + (lane & 15);
            float bv = bias[col];
            #pragma unroll
            for (int r = 0; r < 4; ++r) {
                int row = m0 + wm * (BM / 2) + i * 16 + (lane >> 4) * 4 + r;
                float val = acc[i][j][r] + bv;
                if (OUT_BF16) {
                    ((unsigned short*)Cv)[(size_t)row * N + col] = f2bf(val);
                } else {
                    ((float*)Cv)[(size_t)row * N + col] = val;
                }
            }
        }
    }
}

// ---------------- split-K GEMM2: partial[kz] = A[:, kz*KS:...] @ Bt^T, fp32 -------
__global__ __launch_bounds__(256) void gemm_bt_splitk_kernel(
    const unsigned short* __restrict__ A,
    const unsigned short* __restrict__ Bt,
    float* __restrict__ part,
    int M, int N, int K) {
    constexpr int BM = 64, BN = 64, BK = 64;
    constexpr int FM = 2, FN = 2;
    __shared__ __align__(16) unsigned short As[BM * BK];
    __shared__ __align__(16) unsigned short Bs[BN * BK];
    const int t = threadIdx.x;
    const int lane = t & 63;
    const int wave = t >> 6;
    const int wm = wave >> 1, wn = wave & 1;
    const int m0 = blockIdx.y * BM;
    const int n0 = blockIdx.x * BN;
    const int kz = blockIdx.z;
    const int klen = K / KSPLIT;
    const int kbase = kz * klen;
    f32x4 acc[FM][FN] = {};

    const int srow = t >> 3;
    const int schunk = t & 7;

    for (int k0 = kbase; k0 < kbase + klen; k0 += BK) {
        #pragma unroll
        for (int i = 0; i < BM / 32; ++i) {
            int r = i * 32 + srow;
            int js = schunk ^ (r & 7);
            gload_lds16(A + (size_t)(m0 + r) * K + k0 + js * 8,
                        ((char*)As) + i * 4096 + wave * 1024);
        }
        #pragma unroll
        for (int i = 0; i < BN / 32; ++i) {
            int r = i * 32 + srow;
            int js = schunk ^ (r & 7);
            gload_lds16(Bt + (size_t)(n0 + r) * K + k0 + js * 8,
                        ((char*)Bs) + i * 4096 + wave * 1024);
        }
        __syncthreads();
        #pragma unroll
        for (int kt = 0; kt < 2; ++kt) {
            bf16x8 af[FM], bfr[FN];
            #pragma unroll
            for (int i = 0; i < FM; ++i) {
                int row = wm * 32 + i * 16 + (lane & 15);
                int chunk = (kt * 4 + (lane >> 4)) ^ (row & 7);
                af[i] = *(const bf16x8*)(((const char*)As) + row * 128 + chunk * 16);
            }
            #pragma unroll
            for (int j = 0; j < FN; ++j) {
                int row = wn * 32 + j * 16 + (lane & 15);
                int chunk = (kt * 4 + (lane >> 4)) ^ (row & 7);
                bfr[j] = *(const bf16x8*)(((const char*)Bs) + row * 128 + chunk * 16);
            }
            #pragma unroll
            for (int i = 0; i < FM; ++i)
                #pragma unroll
                for (int j = 0; j < FN; ++j)
                    acc[i][j] = __builtin_amdgcn_mfma_f32_16x16x32_bf16(
                        af[i], bfr[j], acc[i][j], 0, 0, 0);
        }
        __syncthreads();
    }

    float* dst = part + (size_t)kz * M * N;
    #pragma unroll
    for (int i = 0; i < FM; ++i)
        #pragma unroll
        for (int j = 0; j < FN; ++j) {
            int col = n0 + wn * 32 + j * 16 + (lane & 15);
            #pragma unroll
            for (int r = 0; r < 4; ++r) {
                int row = m0 + wm * 32 + i * 16 + (lane >> 4) * 4 + r;
                dst[(size_t)row * N + col] = acc[i][j][r];
            }
        }
}

// ---------------- reduce partials + bias + residual ----------------
__global__ __launch_bounds__(256) void splitk_reduce_kernel(
    const float* __restrict__ part, const float* __restrict__ bias,
    const float* __restrict__ resid, float* __restrict__ out) {
    int idx = blockIdx.x * 256 + threadIdx.x;
    const size_t MN = (size_t)LSEQ * D_MODEL;
    f32x4 a = ((const f32x4*)part)[idx];
    #pragma unroll
    for (int z = 1; z < KSPLIT; ++z) {
        f32x4 p = ((const f32x4*)(part + z * MN))[idx];
        a.x += p.x; a.y += p.y; a.z += p.z; a.w += p.w;
    }
    int col4 = idx & (D_MODEL / 4 - 1);
    f32x4 bv = ((const f32x4*)bias)[col4];
    f32x4 rv = ((const f32x4*)resid)[idx];
    a.x += bv.x + rv.x; a.y += bv.y + rv.y; a.z += bv.z + rv.z; a.w += bv.w + rv.w;
    ((f32x4*)out)[idx] = a;
}

// ---------------- fused: silu(conv3(u)) -> 32-tap causal conv -> gate ----------------
__global__ __launch_bounds__(256) void ssm_fused_kernel(
    const unsigned short* __restrict__ uvg,
    const float* __restrict__ conv_w, const float* __restrict__ conv_b,
    const float* __restrict__ kbuf,
    unsigned short* __restrict__ ybf) {
    int lane = threadIdx.x & 63;
    int wave = threadIdx.x >> 6;
    int c = (blockIdx.x & 31) * 64 + lane;
    int t0 = (blockIdx.x >> 5) * 64 + wave * 16;
    const unsigned short* up = uvg + c;
    const float* kc = kbuf + c;
    float cw0 = conv_w[c * 3 + 0];
    float cw1 = conv_w[c * 3 + 1];
    float cw2 = conv_w[c * 3 + 2];
    float cb  = conv_b[c];

    auto raw = [&](int tt) -> float {
        return (tt >= 0 && tt < LSEQ) ? bf2f(up[(size_t)tt * THREE_INNER]) : 0.f;
    };
    auto clean = [&](float rm1, float r0, float rp1) -> float {
        float a = fmaf(rp1, cw2, fmaf(r0, cw1, fmaf(rm1, cw0, cb)));
        return a * sigm(a);
    };

    float w[16];
    {
        float rm1 = raw(t0 - 1), r0 = raw(t0);
        #pragma unroll
        for (int j = 0; j < 16; ++j) {
            float rp1 = raw(t0 + j + 1);
            w[j] = clean(rm1, r0, rp1);
            rm1 = r0; r0 = rp1;
        }
    }
    float acc[16] = {};
    float q0 = raw(t0), q1 = raw(t0 - 1);
    #pragma unroll
    for (int d = 0; d < SKTAPS; ++d) {
        float kd = kc[(size_t)d * INNER];
        #pragma unroll
        for (int j = 0; j < 16; ++j) acc[j] = fmaf(kd, w[j], acc[j]);
        if (d < SKTAPS - 1) {
            float q2 = raw(t0 - 2 - d);
            float nc = (t0 - 1 - d >= 0) ? clean(q2, q1, q0) : 0.f;
            #pragma unroll
            for (int j = 15; j > 0; --j) w[j] = w[j - 1];
            w[0] = nc;
            q0 = q1; q1 = q2;
        }
    }
    #pragma unroll
    for (int j = 0; j < 16; ++j) {
        size_t tt = (size_t)(t0 + j);
        float v = bf2f(uvg[tt * THREE_INNER + INNER + c]);
        float g = bf2f(uvg[tt * THREE_INNER + 2 * INNER + c]);
        float o = acc[j] * sigm(g) + v * sigm(v);
        ybf[tt * INNER + c] = f2bf(o);
    }
}

extern "C" void kernel_launch(void* const* d_in, const int* in_sizes, int n_in,
                              void* d_out, int out_size, void* d_ws, size_t ws_size,
                              hipStream_t stream) {
    const float* x       = (const float*)d_in[0];
    const float* gamma   = (const float*)d_in[1];
    const float* beta    = (const float*)d_in[2];
    const float* in_w    = (const float*)d_in[3];
    const float* in_b    = (const float*)d_in[4];
    const float* conv_w  = (const float*)d_in[5];
    const float* conv_b  = (const float*)d_in[6];
    const float* A_log   = (const float*)d_in[7];
    const float* B_p     = (const float*)d_in[8];
    const float* C_p     = (const float*)d_in[9];
    const float* D_p     = (const float*)d_in[10];
    const float* out_w   = (const float*)d_in[11];
    const float* out_b   = (const float*)d_in[12];
    float* out = (float*)d_out;

    char* ws = (char*)d_ws;
    unsigned short* h      = (unsigned short*)ws;  ws += (size_t)LSEQ * D_MODEL * 2;
    unsigned short* uvg    = (unsigned short*)ws;  ws += (size_t)LSEQ * THREE_INNER * 2;
    unsigned short* ybf    = (unsigned short*)ws;  ws += (size_t)LSEQ * INNER * 2;
    float*          kbuf   = (float*)ws;           ws += (size_t)SKTAPS * INNER * 4;
    unsigned short* in_wt  = (unsigned short*)ws;  ws += (size_t)THREE_INNER * D_MODEL * 2;
    unsigned short* out_wt = (unsigned short*)ws;  ws += (size_t)D_MODEL * INNER * 2;
    float*          part   = (float*)ws;           ws += (size_t)KSPLIT * LSEQ * D_MODEL * 4;

    // merged preprocessing: both weight transposes + LN + kprec
    prep_kernel<<<3584, 256, 0, stream>>>(in_w, in_wt, out_w, out_wt,
                                          x, gamma, beta, h,
                                          A_log, B_p, C_p, D_p, kbuf);

    {   // GEMM1: (1024x1024) @ (1024x6144) -> uvg (bf16), 128x128 tile, 64x64 wave tiles
        dim3 g(THREE_INNER / 128, LSEQ / 128);
        gemm_bt_kernel<128, 128, true><<<g, 256, 0, stream>>>(h, in_wt, in_b, uvg,
                                                              LSEQ, THREE_INNER, D_MODEL);
    }

    ssm_fused_kernel<<<(LSEQ / 64) * 32, 256, 0, stream>>>(uvg, conv_w, conv_b, kbuf, ybf);

    {   // GEMM2 split-K: (1024x2048) @ (2048x1024) -> 4 partials
        dim3 g(D_MODEL / 64, LSEQ / 64, KSPLIT);
        gemm_bt_splitk_kernel<<<g, 256, 0, stream>>>(ybf, out_wt, part,
                                                     LSEQ, D_MODEL, INNER);
    }
    splitk_reduce_kernel<<<(LSEQ * D_MODEL / 4) / 256, 256, 0, stream>>>(
        part, out_b, x, out);
}

// Round 7
// 84.353 us; speedup vs baseline: 1.1937x; 1.0470x over previous
//
#include <hip/hip_runtime.h>
#include <hip/hip_bf16.h>
#include <math.h>

#define D_MODEL 1024
#define INNER 2048
#define THREE_INNER 6144
#define D_STATE 64
#define LSEQ 1024
#define LN_EPS 1e-5f
#define SKTAPS 32

typedef __attribute__((ext_vector_type(4))) float f32x4;
typedef __attribute__((ext_vector_type(8))) short bf16x8;
typedef __attribute__((ext_vector_type(8))) unsigned short u16x8;

__device__ __forceinline__ float sigm(float x) { return 1.f / (1.f + __expf(-x)); }

__device__ __forceinline__ unsigned short f2bf(float f) {
    unsigned int u = __float_as_uint(f);
    unsigned int r = (u + 0x7FFF + ((u >> 16) & 1)) >> 16;
    return (unsigned short)r;
}
__device__ __forceinline__ float bf2f(unsigned short s) {
    return __uint_as_float(((unsigned int)s) << 16);
}

__device__ __forceinline__ void gload_lds16(const void* gsrc, void* ldst) {
    __builtin_amdgcn_global_load_lds(
        (const __attribute__((address_space(1))) void*)gsrc,
        (__attribute__((address_space(3))) void*)ldst,
        16, 0, 0);
}

// ================= merged preprocessing kernel =================
__device__ __forceinline__ void transpose_tile(
    const float* __restrict__ W, unsigned short* __restrict__ Wt,
    int K, int N, int k0, int n0) {
    __shared__ float tile[64][65];
    int r = threadIdx.x >> 2;
    int seg = threadIdx.x & 3;
    const float* src = W + (size_t)(k0 + r) * N + n0 + seg * 16;
    #pragma unroll
    for (int i = 0; i < 4; ++i) {
        float4 v = *(const float4*)(src + i * 4);
        tile[r][seg * 16 + i * 4 + 0] = v.x;
        tile[r][seg * 16 + i * 4 + 1] = v.y;
        tile[r][seg * 16 + i * 4 + 2] = v.z;
        tile[r][seg * 16 + i * 4 + 3] = v.w;
    }
    __syncthreads();
    int n = r, ks = seg;
    unsigned short pack[16];
    #pragma unroll
    for (int j = 0; j < 16; ++j) pack[j] = f2bf(tile[ks * 16 + j][n]);
    unsigned short* dst = Wt + (size_t)(n0 + n) * K + k0 + ks * 16;
    *(u16x8*)dst       = *(u16x8*)&pack[0];
    *(u16x8*)(dst + 8) = *(u16x8*)&pack[8];
}

__global__ __launch_bounds__(256) void prep_kernel(
    const float* __restrict__ in_w,  unsigned short* __restrict__ in_wt,
    const float* __restrict__ out_w, unsigned short* __restrict__ out_wt,
    const float* __restrict__ x, const float* __restrict__ gamma,
    const float* __restrict__ beta, unsigned short* __restrict__ h,
    const float* __restrict__ A_log, const float* __restrict__ Bp,
    const float* __restrict__ Cp, const float* __restrict__ Dp,
    float* __restrict__ kbuf) {
    int b = blockIdx.x;
    if (b < 1536) {
        int bx = b % 96, by = b / 96;
        transpose_tile(in_w, in_wt, D_MODEL, THREE_INNER, by * 64, bx * 64);
        return;
    }
    if (b < 2048) {
        int b2 = b - 1536;
        int bx = b2 % 16, by = b2 / 16;
        transpose_tile(out_w, out_wt, INNER, D_MODEL, by * 64, bx * 64);
        return;
    }
    if (b < 3072) {
        int row = b - 2048;
        int tid = threadIdx.x;
        const float4 v = ((const float4*)(x + (size_t)row * D_MODEL))[tid];
        float sum = v.x + v.y + v.z + v.w;
        float sq  = v.x*v.x + v.y*v.y + v.z*v.z + v.w*v.w;
        #pragma unroll
        for (int off = 1; off < 64; off <<= 1) {
            sum += __shfl_xor(sum, off);
            sq  += __shfl_xor(sq,  off);
        }
        __shared__ float ssum[4], ssq[4];
        int wave = tid >> 6, lane = tid & 63;
        if (lane == 0) { ssum[wave] = sum; ssq[wave] = sq; }
        __syncthreads();
        sum = ssum[0] + ssum[1] + ssum[2] + ssum[3];
        sq  = ssq[0]  + ssq[1]  + ssq[2]  + ssq[3];
        float mu  = sum * (1.f / D_MODEL);
        float var = sq  * (1.f / D_MODEL) - mu * mu;
        float rstd = rsqrtf(var + LN_EPS);
        const float4 gv = ((const float4*)gamma)[tid];
        const float4 bv = ((const float4*)beta)[tid];
        ushort4 o;
        o.x = f2bf((v.x - mu) * rstd * gv.x + bv.x);
        o.y = f2bf((v.y - mu) * rstd * gv.y + bv.y);
        o.z = f2bf((v.z - mu) * rstd * gv.z + bv.z);
        o.w = f2bf((v.w - mu) * rstd * gv.w + bv.w);
        ((ushort4*)(h + (size_t)row * D_MODEL))[tid] = o;
        return;
    }
    {
        int lane = threadIdx.x & 63;
        int c = (b - 3072) * 4 + (threadIdx.x >> 6);
        float e1 = __expf(-__expf(A_log[c * 64 + lane]));
        float wgt = Bp[c * 64 + lane] * Cp[c * 64 + lane];
        float d0 = Dp[c];
        #pragma unroll
        for (int d = 0; d < SKTAPS; ++d) {
            float s = wgt;
            s += __shfl_xor(s, 32);
            s += __shfl_xor(s, 16);
            s += __shfl_xor(s, 8);
            s += __shfl_xor(s, 4);
            s += __shfl_xor(s, 2);
            s += __shfl_xor(s, 1);
            if (lane == 0) kbuf[(size_t)d * INNER + c] = s + (d == 0 ? d0 : 0.f);
            wgt *= e1;
        }
    }
}

// ---------------- GEMM1: bf16 MFMA, 64x128 tile, 2-phase double-buffered -------
// C(bf16) = A(bf16 [M][K]) @ Bt^T (bf16 [N][K]) + bias
__global__ __launch_bounds__(256) void gemm1_kernel(
    const unsigned short* __restrict__ A,
    const unsigned short* __restrict__ Bt,
    const float* __restrict__ bias,
    unsigned short* __restrict__ C,
    int M, int N, int K) {
    constexpr int BM = 64, BN = 128, BK = 64;
    constexpr int FM = 2, FN = 4;
    __shared__ __align__(16) unsigned short As[2][BM * BK];
    __shared__ __align__(16) unsigned short Bs[2][BN * BK];
    const int t = threadIdx.x;
    const int lane = t & 63;
    const int wave = t >> 6;
    const int wm = wave >> 1, wn = wave & 1;
    const int m0 = blockIdx.y * BM;
    const int n0 = blockIdx.x * BN;
    f32x4 acc[FM][FN] = {};

    const int srow = t >> 3;
    const int schunk = t & 7;

    auto stage = [&](int buf, int k0) {
        #pragma unroll
        for (int i = 0; i < BM / 32; ++i) {
            int r = i * 32 + srow;
            int js = schunk ^ (r & 7);
            gload_lds16(A + (size_t)(m0 + r) * K + k0 + js * 8,
                        ((char*)As[buf]) + i * 4096 + wave * 1024);
        }
        #pragma unroll
        for (int i = 0; i < BN / 32; ++i) {
            int r = i * 32 + srow;
            int js = schunk ^ (r & 7);
            gload_lds16(Bt + (size_t)(n0 + r) * K + k0 + js * 8,
                        ((char*)Bs[buf]) + i * 4096 + wave * 1024);
        }
    };
    auto compute = [&](int buf) {
        #pragma unroll
        for (int kt = 0; kt < 2; ++kt) {
            bf16x8 af[FM], bfr[FN];
            #pragma unroll
            for (int i = 0; i < FM; ++i) {
                int row = wm * (BM / 2) + i * 16 + (lane & 15);
                int chunk = (kt * 4 + (lane >> 4)) ^ (row & 7);
                af[i] = *(const bf16x8*)(((const char*)As[buf]) + row * 128 + chunk * 16);
            }
            #pragma unroll
            for (int j = 0; j < FN; ++j) {
                int row = wn * (BN / 2) + j * 16 + (lane & 15);
                int chunk = (kt * 4 + (lane >> 4)) ^ (row & 7);
                bfr[j] = *(const bf16x8*)(((const char*)Bs[buf]) + row * 128 + chunk * 16);
            }
            #pragma unroll
            for (int i = 0; i < FM; ++i)
                #pragma unroll
                for (int j = 0; j < FN; ++j)
                    acc[i][j] = __builtin_amdgcn_mfma_f32_16x16x32_bf16(
                        af[i], bfr[j], acc[i][j], 0, 0, 0);
        }
    };

    stage(0, 0);
    __syncthreads();
    int cur = 0;
    const int NT = K / BK;
    for (int tt = 0; tt + 1 < NT; ++tt) {
        stage(cur ^ 1, (tt + 1) * BK);   // prefetch overlaps compute + drain
        compute(cur);
        __syncthreads();
        cur ^= 1;
    }
    compute(cur);

    #pragma unroll
    for (int i = 0; i < FM; ++i) {
        #pragma unroll
        for (int j = 0; j < FN; ++j) {
            int col = n0 + wn * (BN / 2) + j * 16 + (lane & 15);
            float bv = bias[col];
            #pragma unroll
            for (int r = 0; r < 4; ++r) {
                int row = m0 + wm * (BM / 2) + i * 16 + (lane >> 4) * 4 + r;
                C[(size_t)row * N + col] = f2bf(acc[i][j][r] + bv);
            }
        }
    }
}

// ---------------- GEMM2: in-block split-K (8 waves = 2 K-halves x 2x2), dbuf ----
// out = A(bf16 [M][K]) @ Bt^T (bf16 [N][K]) + bias + resid, fp32 out
__global__ __launch_bounds__(512) void gemm2_kernel(
    const unsigned short* __restrict__ A,
    const unsigned short* __restrict__ Bt,
    const float* __restrict__ bias,
    const float* __restrict__ resid,
    float* __restrict__ out) {
    constexpr int N = D_MODEL, K = INNER, BK = 64, KH = K / 2;
    __shared__ __align__(16) unsigned short As[2][2][64 * 64];  // [buf][kz]
    __shared__ __align__(16) unsigned short Bs[2][2][64 * 64];
    const int t = threadIdx.x;
    const int lane = t & 63;
    const int wave = t >> 6;      // 0..7
    const int kz = wave >> 2;     // K-half
    const int w2 = wave & 3;
    const int wm = w2 >> 1, wn = w2 & 1;
    const int m0 = blockIdx.y * 64, n0 = blockIdx.x * 64;
    f32x4 acc[2][2] = {};
    const int t4 = t & 255;
    const int srow = t4 >> 3, schunk = t4 & 7;
    const unsigned short* Abase = A + (size_t)kz * KH;
    const unsigned short* Bbase = Bt + (size_t)kz * KH;

    auto stage = [&](int buf, int k0) {
        #pragma unroll
        for (int i = 0; i < 2; ++i) {
            int r = i * 32 + srow;
            int js = schunk ^ (r & 7);
            gload_lds16(Abase + (size_t)(m0 + r) * K + k0 + js * 8,
                        ((char*)As[buf][kz]) + i * 4096 + w2 * 1024);
            gload_lds16(Bbase + (size_t)(n0 + r) * K + k0 + js * 8,
                        ((char*)Bs[buf][kz]) + i * 4096 + w2 * 1024);
        }
    };
    auto compute = [&](int buf) {
        #pragma unroll
        for (int kt = 0; kt < 2; ++kt) {
            bf16x8 af[2], bfr[2];
            #pragma unroll
            for (int i = 0; i < 2; ++i) {
                int row = wm * 32 + i * 16 + (lane & 15);
                int chunk = (kt * 4 + (lane >> 4)) ^ (row & 7);
                af[i] = *(const bf16x8*)(((const char*)As[buf][kz]) + row * 128 + chunk * 16);
            }
            #pragma unroll
            for (int j = 0; j < 2; ++j) {
                int row = wn * 32 + j * 16 + (lane & 15);
                int chunk = (kt * 4 + (lane >> 4)) ^ (row & 7);
                bfr[j] = *(const bf16x8*)(((const char*)Bs[buf][kz]) + row * 128 + chunk * 16);
            }
            #pragma unroll
            for (int i = 0; i < 2; ++i)
                #pragma unroll
                for (int j = 0; j < 2; ++j)
                    acc[i][j] = __builtin_amdgcn_mfma_f32_16x16x32_bf16(
                        af[i], bfr[j], acc[i][j], 0, 0, 0);
        }
    };

    stage(0, 0);
    __syncthreads();
    int cur = 0;
    constexpr int NT = KH / BK;   // 16
    for (int tt = 0; tt + 1 < NT; ++tt) {
        stage(cur ^ 1, (tt + 1) * BK);
        compute(cur);
        __syncthreads();
        cur ^= 1;
    }
    compute(cur);
    __syncthreads();   // all LDS reads complete before scratch reuse

    // combine the two K-halves via LDS scratch (reuse As; stride 17 = conflict-free)
    float* scratch = (float*)&As[0][0][0];
    if (kz == 1) {
        #pragma unroll
        for (int i = 0; i < 2; ++i)
            #pragma unroll
            for (int j = 0; j < 2; ++j)
                #pragma unroll
                for (int r = 0; r < 4; ++r)
                    scratch[(w2 * 64 + lane) * 17 + (i * 2 + j) * 4 + r] = acc[i][j][r];
    }
    __syncthreads();
    if (kz == 0) {
        #pragma unroll
        for (int i = 0; i < 2; ++i)
            #pragma unroll
            for (int j = 0; j < 2; ++j) {
                int col = n0 + wn * 32 + j * 16 + (lane & 15);
                float bv = bias[col];
                #pragma unroll
                for (int r = 0; r < 4; ++r) {
                    int row = m0 + wm * 32 + i * 16 + (lane >> 4) * 4 + r;
                    float val = acc[i][j][r]
                              + scratch[(w2 * 64 + lane) * 17 + (i * 2 + j) * 4 + r]
                              + bv + resid[(size_t)row * N + col];
                    out[(size_t)row * N + col] = val;
                }
            }
    }
}

// ---------------- fused: silu(conv3(u)) -> 32-tap causal conv -> gate ----------------
__global__ __launch_bounds__(256) void ssm_fused_kernel(
    const unsigned short* __restrict__ uvg,
    const float* __restrict__ conv_w, const float* __restrict__ conv_b,
    const float* __restrict__ kbuf,
    unsigned short* __restrict__ ybf) {
    int lane = threadIdx.x & 63;
    int wave = threadIdx.x >> 6;
    int c = (blockIdx.x & 31) * 64 + lane;
    int t0 = (blockIdx.x >> 5) * 64 + wave * 16;
    const unsigned short* up = uvg + c;
    const float* kc = kbuf + c;
    float cw0 = conv_w[c * 3 + 0];
    float cw1 = conv_w[c * 3 + 1];
    float cw2 = conv_w[c * 3 + 2];
    float cb  = conv_b[c];

    auto raw = [&](int tt) -> float {
        return (tt >= 0 && tt < LSEQ) ? bf2f(up[(size_t)tt * THREE_INNER]) : 0.f;
    };
    auto clean = [&](float rm1, float r0, float rp1) -> float {
        float a = fmaf(rp1, cw2, fmaf(r0, cw1, fmaf(rm1, cw0, cb)));
        return a * sigm(a);
    };

    float w[16];
    {
        float rm1 = raw(t0 - 1), r0 = raw(t0);
        #pragma unroll
        for (int j = 0; j < 16; ++j) {
            float rp1 = raw(t0 + j + 1);
            w[j] = clean(rm1, r0, rp1);
            rm1 = r0; r0 = rp1;
        }
    }
    float acc[16] = {};
    float q0 = raw(t0), q1 = raw(t0 - 1);
    #pragma unroll
    for (int d = 0; d < SKTAPS; ++d) {
        float kd = kc[(size_t)d * INNER];
        #pragma unroll
        for (int j = 0; j < 16; ++j) acc[j] = fmaf(kd, w[j], acc[j]);
        if (d < SKTAPS - 1) {
            float q2 = raw(t0 - 2 - d);
            float nc = (t0 - 1 - d >= 0) ? clean(q2, q1, q0) : 0.f;
            #pragma unroll
            for (int j = 15; j > 0; --j) w[j] = w[j - 1];
            w[0] = nc;
            q0 = q1; q1 = q2;
        }
    }
    #pragma unroll
    for (int j = 0; j < 16; ++j) {
        size_t tt = (size_t)(t0 + j);
        float v = bf2f(uvg[tt * THREE_INNER + INNER + c]);
        float g = bf2f(uvg[tt * THREE_INNER + 2 * INNER + c]);
        float o = acc[j] * sigm(g) + v * sigm(v);
        ybf[tt * INNER + c] = f2bf(o);
    }
}

extern "C" void kernel_launch(void* const* d_in, const int* in_sizes, int n_in,
                              void* d_out, int out_size, void* d_ws, size_t ws_size,
                              hipStream_t stream) {
    const float* x       = (const float*)d_in[0];
    const float* gamma   = (const float*)d_in[1];
    const float* beta    = (const float*)d_in[2];
    const float* in_w    = (const float*)d_in[3];
    const float* in_b    = (const float*)d_in[4];
    const float* conv_w  = (const float*)d_in[5];
    const float* conv_b  = (const float*)d_in[6];
    const float* A_log   = (const float*)d_in[7];
    const float* B_p     = (const float*)d_in[8];
    const float* C_p     = (const float*)d_in[9];
    const float* D_p     = (const float*)d_in[10];
    const float* out_w   = (const float*)d_in[11];
    const float* out_b   = (const float*)d_in[12];
    float* out = (float*)d_out;

    char* ws = (char*)d_ws;
    unsigned short* h      = (unsigned short*)ws;  ws += (size_t)LSEQ * D_MODEL * 2;
    unsigned short* uvg    = (unsigned short*)ws;  ws += (size_t)LSEQ * THREE_INNER * 2;
    unsigned short* ybf    = (unsigned short*)ws;  ws += (size_t)LSEQ * INNER * 2;
    float*          kbuf   = (float*)ws;           ws += (size_t)SKTAPS * INNER * 4;
    unsigned short* in_wt  = (unsigned short*)ws;  ws += (size_t)THREE_INNER * D_MODEL * 2;
    unsigned short* out_wt = (unsigned short*)ws;  ws += (size_t)D_MODEL * INNER * 2;

    // merged preprocessing: both weight transposes + LN + kprec
    prep_kernel<<<3584, 256, 0, stream>>>(in_w, in_wt, out_w, out_wt,
                                          x, gamma, beta, h,
                                          A_log, B_p, C_p, D_p, kbuf);

    {   // GEMM1: (1024x1024) @ (1024x6144) -> uvg (bf16), 64x128 tile, 768 blocks
        dim3 g(THREE_INNER / 128, LSEQ / 64);
        gemm1_kernel<<<g, 256, 0, stream>>>(h, in_wt, in_b, uvg,
                                            LSEQ, THREE_INNER, D_MODEL);
    }

    ssm_fused_kernel<<<(LSEQ / 64) * 32, 256, 0, stream>>>(uvg, conv_w, conv_b, kbuf, ybf);

    {   // GEMM2: (1024x2048) @ (2048x1024) + out_b + x -> out, in-block split-K
        dim3 g(D_MODEL / 64, LSEQ / 64);
        gemm2_kernel<<<g, 512, 0, stream>>>(ybf, out_wt, out_b, x, out);
    }
}

// Round 8
// 83.231 us; speedup vs baseline: 1.2097x; 1.0135x over previous
//
#include <hip/hip_runtime.h>
#include <hip/hip_bf16.h>
#include <math.h>

#define D_MODEL 1024
#define INNER 2048
#define THREE_INNER 6144
#define D_STATE 64
#define LSEQ 1024
#define LN_EPS 1e-5f
#define SKTAPS 32

typedef __attribute__((ext_vector_type(4))) float f32x4;
typedef __attribute__((ext_vector_type(8))) short bf16x8;
typedef __attribute__((ext_vector_type(8))) unsigned short u16x8;

__device__ __forceinline__ float sigm(float x) { return 1.f / (1.f + __expf(-x)); }

__device__ __forceinline__ unsigned short f2bf(float f) {
    unsigned int u = __float_as_uint(f);
    unsigned int r = (u + 0x7FFF + ((u >> 16) & 1)) >> 16;
    return (unsigned short)r;
}
__device__ __forceinline__ float bf2f(unsigned short s) {
    return __uint_as_float(((unsigned int)s) << 16);
}

__device__ __forceinline__ void gload_lds16(const void* gsrc, void* ldst) {
    __builtin_amdgcn_global_load_lds(
        (const __attribute__((address_space(1))) void*)gsrc,
        (__attribute__((address_space(3))) void*)ldst,
        16, 0, 0);
}

// ================= merged preprocessing kernel =================
__device__ __forceinline__ void transpose_tile(
    const float* __restrict__ W, unsigned short* __restrict__ Wt,
    int K, int N, int k0, int n0) {
    __shared__ float tile[64][65];
    int r = threadIdx.x >> 2;
    int seg = threadIdx.x & 3;
    const float* src = W + (size_t)(k0 + r) * N + n0 + seg * 16;
    #pragma unroll
    for (int i = 0; i < 4; ++i) {
        float4 v = *(const float4*)(src + i * 4);
        tile[r][seg * 16 + i * 4 + 0] = v.x;
        tile[r][seg * 16 + i * 4 + 1] = v.y;
        tile[r][seg * 16 + i * 4 + 2] = v.z;
        tile[r][seg * 16 + i * 4 + 3] = v.w;
    }
    __syncthreads();
    int n = r, ks = seg;
    unsigned short pack[16];
    #pragma unroll
    for (int j = 0; j < 16; ++j) pack[j] = f2bf(tile[ks * 16 + j][n]);
    unsigned short* dst = Wt + (size_t)(n0 + n) * K + k0 + ks * 16;
    *(u16x8*)dst       = *(u16x8*)&pack[0];
    *(u16x8*)(dst + 8) = *(u16x8*)&pack[8];
}

__global__ __launch_bounds__(256) void prep_kernel(
    const float* __restrict__ in_w,  unsigned short* __restrict__ in_wt,
    const float* __restrict__ out_w, unsigned short* __restrict__ out_wt,
    const float* __restrict__ x, const float* __restrict__ gamma,
    const float* __restrict__ beta, unsigned short* __restrict__ h,
    const float* __restrict__ A_log, const float* __restrict__ Bp,
    const float* __restrict__ Cp, const float* __restrict__ Dp,
    float* __restrict__ kbuf) {
    int b = blockIdx.x;
    if (b < 1536) {
        int bx = b % 96, by = b / 96;
        transpose_tile(in_w, in_wt, D_MODEL, THREE_INNER, by * 64, bx * 64);
        return;
    }
    if (b < 2048) {
        int b2 = b - 1536;
        int bx = b2 % 16, by = b2 / 16;
        transpose_tile(out_w, out_wt, INNER, D_MODEL, by * 64, bx * 64);
        return;
    }
    if (b < 3072) {
        int row = b - 2048;
        int tid = threadIdx.x;
        const float4 v = ((const float4*)(x + (size_t)row * D_MODEL))[tid];
        float sum = v.x + v.y + v.z + v.w;
        float sq  = v.x*v.x + v.y*v.y + v.z*v.z + v.w*v.w;
        #pragma unroll
        for (int off = 1; off < 64; off <<= 1) {
            sum += __shfl_xor(sum, off);
            sq  += __shfl_xor(sq,  off);
        }
        __shared__ float ssum[4], ssq[4];
        int wave = tid >> 6, lane = tid & 63;
        if (lane == 0) { ssum[wave] = sum; ssq[wave] = sq; }
        __syncthreads();
        sum = ssum[0] + ssum[1] + ssum[2] + ssum[3];
        sq  = ssq[0]  + ssq[1]  + ssq[2]  + ssq[3];
        float mu  = sum * (1.f / D_MODEL);
        float var = sq  * (1.f / D_MODEL) - mu * mu;
        float rstd = rsqrtf(var + LN_EPS);
        const float4 gv = ((const float4*)gamma)[tid];
        const float4 bv = ((const float4*)beta)[tid];
        ushort4 o;
        o.x = f2bf((v.x - mu) * rstd * gv.x + bv.x);
        o.y = f2bf((v.y - mu) * rstd * gv.y + bv.y);
        o.z = f2bf((v.z - mu) * rstd * gv.z + bv.z);
        o.w = f2bf((v.w - mu) * rstd * gv.w + bv.w);
        ((ushort4*)(h + (size_t)row * D_MODEL))[tid] = o;
        return;
    }
    {
        int lane = threadIdx.x & 63;
        int c = (b - 3072) * 4 + (threadIdx.x >> 6);
        float e1 = __expf(-__expf(A_log[c * 64 + lane]));
        float wgt = Bp[c * 64 + lane] * Cp[c * 64 + lane];
        float d0 = Dp[c];
        #pragma unroll
        for (int d = 0; d < SKTAPS; ++d) {
            float s = wgt;
            s += __shfl_xor(s, 32);
            s += __shfl_xor(s, 16);
            s += __shfl_xor(s, 8);
            s += __shfl_xor(s, 4);
            s += __shfl_xor(s, 2);
            s += __shfl_xor(s, 1);
            if (lane == 0) kbuf[(size_t)d * INNER + c] = s + (d == 0 ? d0 : 0.f);
            wgt *= e1;
        }
    }
}

// ---------------- GEMM1: bf16 MFMA, 64x128 tile, 2-phase dbuf, XCD-chunked ----
// grid: 768 blocks 1D. Per-XCD chunk: 8 m-blocks x 12 n-blocks
// -> A 1MB + B 3MB per XCD L2 (4MB) resident.
__global__ __launch_bounds__(256) void gemm1_kernel(
    const unsigned short* __restrict__ A,
    const unsigned short* __restrict__ Bt,
    const float* __restrict__ bias,
    unsigned short* __restrict__ C,
    int M, int N, int K) {
    constexpr int BM = 64, BN = 128, BK = 64;
    constexpr int FM = 2, FN = 4;
    __shared__ __align__(16) unsigned short As[2][BM * BK];
    __shared__ __align__(16) unsigned short Bs[2][BN * BK];
    const int t = threadIdx.x;
    const int lane = t & 63;
    const int wave = t >> 6;
    const int wm = wave >> 1, wn = wave & 1;
    // XCD-chunked swizzle: xcd = bid&7 gets a contiguous 8m x 12n region
    const int bid = blockIdx.x;
    const int xcd = bid & 7, idx = bid >> 3;           // idx in [0,96)
    const int mi = ((xcd & 1) << 3) + (idx & 7);       // 16 m-blocks
    const int ni = (xcd >> 1) * 12 + (idx >> 3);       // 48 n-blocks
    const int m0 = mi * BM;
    const int n0 = ni * BN;
    f32x4 acc[FM][FN] = {};

    const int srow = t >> 3;
    const int schunk = t & 7;

    auto stage = [&](int buf, int k0) {
        #pragma unroll
        for (int i = 0; i < BM / 32; ++i) {
            int r = i * 32 + srow;
            int js = schunk ^ (r & 7);
            gload_lds16(A + (size_t)(m0 + r) * K + k0 + js * 8,
                        ((char*)As[buf]) + i * 4096 + wave * 1024);
        }
        #pragma unroll
        for (int i = 0; i < BN / 32; ++i) {
            int r = i * 32 + srow;
            int js = schunk ^ (r & 7);
            gload_lds16(Bt + (size_t)(n0 + r) * K + k0 + js * 8,
                        ((char*)Bs[buf]) + i * 4096 + wave * 1024);
        }
    };
    auto compute = [&](int buf) {
        #pragma unroll
        for (int kt = 0; kt < 2; ++kt) {
            bf16x8 af[FM], bfr[FN];
            #pragma unroll
            for (int i = 0; i < FM; ++i) {
                int row = wm * (BM / 2) + i * 16 + (lane & 15);
                int chunk = (kt * 4 + (lane >> 4)) ^ (row & 7);
                af[i] = *(const bf16x8*)(((const char*)As[buf]) + row * 128 + chunk * 16);
            }
            #pragma unroll
            for (int j = 0; j < FN; ++j) {
                int row = wn * (BN / 2) + j * 16 + (lane & 15);
                int chunk = (kt * 4 + (lane >> 4)) ^ (row & 7);
                bfr[j] = *(const bf16x8*)(((const char*)Bs[buf]) + row * 128 + chunk * 16);
            }
            #pragma unroll
            for (int i = 0; i < FM; ++i)
                #pragma unroll
                for (int j = 0; j < FN; ++j)
                    acc[i][j] = __builtin_amdgcn_mfma_f32_16x16x32_bf16(
                        af[i], bfr[j], acc[i][j], 0, 0, 0);
        }
    };

    stage(0, 0);
    __syncthreads();
    int cur = 0;
    const int NT = K / BK;
    for (int tt = 0; tt + 1 < NT; ++tt) {
        stage(cur ^ 1, (tt + 1) * BK);
        compute(cur);
        __syncthreads();
        cur ^= 1;
    }
    compute(cur);

    #pragma unroll
    for (int i = 0; i < FM; ++i) {
        #pragma unroll
        for (int j = 0; j < FN; ++j) {
            int col = n0 + wn * (BN / 2) + j * 16 + (lane & 15);
            float bv = bias[col];
            #pragma unroll
            for (int r = 0; r < 4; ++r) {
                int row = m0 + wm * (BM / 2) + i * 16 + (lane >> 4) * 4 + r;
                C[(size_t)row * N + col] = f2bf(acc[i][j][r] + bv);
            }
        }
    }
}

// ---------------- GEMM2: in-block split-K, dbuf, XCD-chunked ----------------
// grid: 256 blocks 1D. Per-XCD chunk: 8m x 4n -> A 2MB + B 1MB per XCD L2.
__global__ __launch_bounds__(512) void gemm2_kernel(
    const unsigned short* __restrict__ A,
    const unsigned short* __restrict__ Bt,
    const float* __restrict__ bias,
    const float* __restrict__ resid,
    float* __restrict__ out) {
    constexpr int N = D_MODEL, K = INNER, BK = 64, KH = K / 2;
    __shared__ __align__(16) unsigned short As[2][2][64 * 64];  // [buf][kz]
    __shared__ __align__(16) unsigned short Bs[2][2][64 * 64];
    const int t = threadIdx.x;
    const int lane = t & 63;
    const int wave = t >> 6;
    const int kz = wave >> 2;
    const int w2 = wave & 3;
    const int wm = w2 >> 1, wn = w2 & 1;
    const int bid = blockIdx.x;
    const int xcd = bid & 7, idx = bid >> 3;           // idx in [0,32)
    const int mi = ((xcd & 1) << 3) + (idx & 7);       // 16 m-blocks
    const int ni = (xcd >> 1) * 4 + (idx >> 3);        // 16 n-blocks
    const int m0 = mi * 64, n0 = ni * 64;
    f32x4 acc[2][2] = {};
    const int t4 = t & 255;
    const int srow = t4 >> 3, schunk = t4 & 7;
    const unsigned short* Abase = A + (size_t)kz * KH;
    const unsigned short* Bbase = Bt + (size_t)kz * KH;

    auto stage = [&](int buf, int k0) {
        #pragma unroll
        for (int i = 0; i < 2; ++i) {
            int r = i * 32 + srow;
            int js = schunk ^ (r & 7);
            gload_lds16(Abase + (size_t)(m0 + r) * K + k0 + js * 8,
                        ((char*)As[buf][kz]) + i * 4096 + w2 * 1024);
            gload_lds16(Bbase + (size_t)(n0 + r) * K + k0 + js * 8,
                        ((char*)Bs[buf][kz]) + i * 4096 + w2 * 1024);
        }
    };
    auto compute = [&](int buf) {
        #pragma unroll
        for (int kt = 0; kt < 2; ++kt) {
            bf16x8 af[2], bfr[2];
            #pragma unroll
            for (int i = 0; i < 2; ++i) {
                int row = wm * 32 + i * 16 + (lane & 15);
                int chunk = (kt * 4 + (lane >> 4)) ^ (row & 7);
                af[i] = *(const bf16x8*)(((const char*)As[buf][kz]) + row * 128 + chunk * 16);
            }
            #pragma unroll
            for (int j = 0; j < 2; ++j) {
                int row = wn * 32 + j * 16 + (lane & 15);
                int chunk = (kt * 4 + (lane >> 4)) ^ (row & 7);
                bfr[j] = *(const bf16x8*)(((const char*)Bs[buf][kz]) + row * 128 + chunk * 16);
            }
            #pragma unroll
            for (int i = 0; i < 2; ++i)
                #pragma unroll
                for (int j = 0; j < 2; ++j)
                    acc[i][j] = __builtin_amdgcn_mfma_f32_16x16x32_bf16(
                        af[i], bfr[j], acc[i][j], 0, 0, 0);
        }
    };

    stage(0, 0);
    __syncthreads();
    int cur = 0;
    constexpr int NT = KH / BK;
    for (int tt = 0; tt + 1 < NT; ++tt) {
        stage(cur ^ 1, (tt + 1) * BK);
        compute(cur);
        __syncthreads();
        cur ^= 1;
    }
    compute(cur);
    __syncthreads();

    float* scratch = (float*)&As[0][0][0];
    if (kz == 1) {
        #pragma unroll
        for (int i = 0; i < 2; ++i)
            #pragma unroll
            for (int j = 0; j < 2; ++j)
                #pragma unroll
                for (int r = 0; r < 4; ++r)
                    scratch[(w2 * 64 + lane) * 17 + (i * 2 + j) * 4 + r] = acc[i][j][r];
    }
    __syncthreads();
    if (kz == 0) {
        #pragma unroll
        for (int i = 0; i < 2; ++i)
            #pragma unroll
            for (int j = 0; j < 2; ++j) {
                int col = n0 + wn * 32 + j * 16 + (lane & 15);
                float bv = bias[col];
                #pragma unroll
                for (int r = 0; r < 4; ++r) {
                    int row = m0 + wm * 32 + i * 16 + (lane >> 4) * 4 + r;
                    float val = acc[i][j][r]
                              + scratch[(w2 * 64 + lane) * 17 + (i * 2 + j) * 4 + r]
                              + bv + resid[(size_t)row * N + col];
                    out[(size_t)row * N + col] = val;
                }
            }
    }
}

// ---------------- fused: silu(conv3(u)) -> 32-tap causal conv -> gate ----------------
__global__ __launch_bounds__(256) void ssm_fused_kernel(
    const unsigned short* __restrict__ uvg,
    const float* __restrict__ conv_w, const float* __restrict__ conv_b,
    const float* __restrict__ kbuf,
    unsigned short* __restrict__ ybf) {
    int lane = threadIdx.x & 63;
    int wave = threadIdx.x >> 6;
    int c = (blockIdx.x & 31) * 64 + lane;
    int t0 = (blockIdx.x >> 5) * 64 + wave * 16;
    const unsigned short* up = uvg + c;
    const float* kc = kbuf + c;
    float cw0 = conv_w[c * 3 + 0];
    float cw1 = conv_w[c * 3 + 1];
    float cw2 = conv_w[c * 3 + 2];
    float cb  = conv_b[c];

    auto raw = [&](int tt) -> float {
        return (tt >= 0 && tt < LSEQ) ? bf2f(up[(size_t)tt * THREE_INNER]) : 0.f;
    };
    auto clean = [&](float rm1, float r0, float rp1) -> float {
        float a = fmaf(rp1, cw2, fmaf(r0, cw1, fmaf(rm1, cw0, cb)));
        return a * sigm(a);
    };

    float w[16];
    {
        float rm1 = raw(t0 - 1), r0 = raw(t0);
        #pragma unroll
        for (int j = 0; j < 16; ++j) {
            float rp1 = raw(t0 + j + 1);
            w[j] = clean(rm1, r0, rp1);
            rm1 = r0; r0 = rp1;
        }
    }
    float acc[16] = {};
    float q0 = raw(t0), q1 = raw(t0 - 1);
    #pragma unroll
    for (int d = 0; d < SKTAPS; ++d) {
        float kd = kc[(size_t)d * INNER];
        #pragma unroll
        for (int j = 0; j < 16; ++j) acc[j] = fmaf(kd, w[j], acc[j]);
        if (d < SKTAPS - 1) {
            float q2 = raw(t0 - 2 - d);
            float nc = (t0 - 1 - d >= 0) ? clean(q2, q1, q0) : 0.f;
            #pragma unroll
            for (int j = 15; j > 0; --j) w[j] = w[j - 1];
            w[0] = nc;
            q0 = q1; q1 = q2;
        }
    }
    #pragma unroll
    for (int j = 0; j < 16; ++j) {
        size_t tt = (size_t)(t0 + j);
        float v = bf2f(uvg[tt * THREE_INNER + INNER + c]);
        float g = bf2f(uvg[tt * THREE_INNER + 2 * INNER + c]);
        float o = acc[j] * sigm(g) + v * sigm(v);
        ybf[tt * INNER + c] = f2bf(o);
    }
}

extern "C" void kernel_launch(void* const* d_in, const int* in_sizes, int n_in,
                              void* d_out, int out_size, void* d_ws, size_t ws_size,
                              hipStream_t stream) {
    const float* x       = (const float*)d_in[0];
    const float* gamma   = (const float*)d_in[1];
    const float* beta    = (const float*)d_in[2];
    const float* in_w    = (const float*)d_in[3];
    const float* in_b    = (const float*)d_in[4];
    const float* conv_w  = (const float*)d_in[5];
    const float* conv_b  = (const float*)d_in[6];
    const float* A_log   = (const float*)d_in[7];
    const float* B_p     = (const float*)d_in[8];
    const float* C_p     = (const float*)d_in[9];
    const float* D_p     = (const float*)d_in[10];
    const float* out_w   = (const float*)d_in[11];
    const float* out_b   = (const float*)d_in[12];
    float* out = (float*)d_out;

    char* ws = (char*)d_ws;
    unsigned short* h      = (unsigned short*)ws;  ws += (size_t)LSEQ * D_MODEL * 2;
    unsigned short* uvg    = (unsigned short*)ws;  ws += (size_t)LSEQ * THREE_INNER * 2;
    unsigned short* ybf    = (unsigned short*)ws;  ws += (size_t)LSEQ * INNER * 2;
    float*          kbuf   = (float*)ws;           ws += (size_t)SKTAPS * INNER * 4;
    unsigned short* in_wt  = (unsigned short*)ws;  ws += (size_t)THREE_INNER * D_MODEL * 2;
    unsigned short* out_wt = (unsigned short*)ws;  ws += (size_t)D_MODEL * INNER * 2;

    prep_kernel<<<3584, 256, 0, stream>>>(in_w, in_wt, out_w, out_wt,
                                          x, gamma, beta, h,
                                          A_log, B_p, C_p, D_p, kbuf);

    {   // GEMM1: (1024x1024) @ (1024x6144) -> uvg (bf16), XCD-chunked 1D grid
        gemm1_kernel<<<768, 256, 0, stream>>>(h, in_wt, in_b, uvg,
                                              LSEQ, THREE_INNER, D_MODEL);
    }

    ssm_fused_kernel<<<(LSEQ / 64) * 32, 256, 0, stream>>>(uvg, conv_w, conv_b, kbuf, ybf);

    {   // GEMM2: (1024x2048) @ (2048x1024) + out_b + x -> out, XCD-chunked
        gemm2_kernel<<<256, 512, 0, stream>>>(ybf, out_wt, out_b, x, out);
    }
}

// Round 9
// 78.506 us; speedup vs baseline: 1.2826x; 1.0602x over previous
//
#include <hip/hip_runtime.h>
#include <hip/hip_bf16.h>
#include <math.h>

#define D_MODEL 1024
#define INNER 2048
#define THREE_INNER 6144
#define D_STATE 64
#define LSEQ 1024
#define LN_EPS 1e-5f
#define SKTAPS 32

typedef __attribute__((ext_vector_type(4))) float f32x4;
typedef __attribute__((ext_vector_type(8))) short bf16x8;
typedef __attribute__((ext_vector_type(8))) unsigned short u16x8;

__device__ __forceinline__ float sigm(float x) { return 1.f / (1.f + __expf(-x)); }

__device__ __forceinline__ unsigned short f2bf(float f) {
    unsigned int u = __float_as_uint(f);
    unsigned int r = (u + 0x7FFF + ((u >> 16) & 1)) >> 16;
    return (unsigned short)r;
}
__device__ __forceinline__ float bf2f(unsigned short s) {
    return __uint_as_float(((unsigned int)s) << 16);
}

__device__ __forceinline__ void gload_lds16(const void* gsrc, void* ldst) {
    __builtin_amdgcn_global_load_lds(
        (const __attribute__((address_space(1))) void*)gsrc,
        (__attribute__((address_space(3))) void*)ldst,
        16, 0, 0);
}

// ================= merged preprocessing kernel =================
__device__ __forceinline__ void transpose_tile(
    const float* __restrict__ W, unsigned short* __restrict__ Wt,
    int K, int N, int k0, int n0) {
    __shared__ float tile[64][65];
    int r = threadIdx.x >> 2;
    int seg = threadIdx.x & 3;
    const float* src = W + (size_t)(k0 + r) * N + n0 + seg * 16;
    #pragma unroll
    for (int i = 0; i < 4; ++i) {
        float4 v = *(const float4*)(src + i * 4);
        tile[r][seg * 16 + i * 4 + 0] = v.x;
        tile[r][seg * 16 + i * 4 + 1] = v.y;
        tile[r][seg * 16 + i * 4 + 2] = v.z;
        tile[r][seg * 16 + i * 4 + 3] = v.w;
    }
    __syncthreads();
    int n = r, ks = seg;
    unsigned short pack[16];
    #pragma unroll
    for (int j = 0; j < 16; ++j) pack[j] = f2bf(tile[ks * 16 + j][n]);
    unsigned short* dst = Wt + (size_t)(n0 + n) * K + k0 + ks * 16;
    *(u16x8*)dst       = *(u16x8*)&pack[0];
    *(u16x8*)(dst + 8) = *(u16x8*)&pack[8];
}

__global__ __launch_bounds__(256) void prep_kernel(
    const float* __restrict__ in_w,  unsigned short* __restrict__ in_wt,
    const float* __restrict__ out_w, unsigned short* __restrict__ out_wt,
    const float* __restrict__ x, const float* __restrict__ gamma,
    const float* __restrict__ beta, unsigned short* __restrict__ h,
    const float* __restrict__ A_log, const float* __restrict__ Bp,
    const float* __restrict__ Cp, const float* __restrict__ Dp,
    float* __restrict__ kbuf) {
    int b = blockIdx.x;
    if (b < 1536) {
        int bx = b % 96, by = b / 96;
        transpose_tile(in_w, in_wt, D_MODEL, THREE_INNER, by * 64, bx * 64);
        return;
    }
    if (b < 2048) {
        int b2 = b - 1536;
        int bx = b2 % 16, by = b2 / 16;
        transpose_tile(out_w, out_wt, INNER, D_MODEL, by * 64, bx * 64);
        return;
    }
    if (b < 3072) {
        int row = b - 2048;
        int tid = threadIdx.x;
        const float4 v = ((const float4*)(x + (size_t)row * D_MODEL))[tid];
        float sum = v.x + v.y + v.z + v.w;
        float sq  = v.x*v.x + v.y*v.y + v.z*v.z + v.w*v.w;
        #pragma unroll
        for (int off = 1; off < 64; off <<= 1) {
            sum += __shfl_xor(sum, off);
            sq  += __shfl_xor(sq,  off);
        }
        __shared__ float ssum[4], ssq[4];
        int wave = tid >> 6, lane = tid & 63;
        if (lane == 0) { ssum[wave] = sum; ssq[wave] = sq; }
        __syncthreads();
        sum = ssum[0] + ssum[1] + ssum[2] + ssum[3];
        sq  = ssq[0]  + ssq[1]  + ssq[2]  + ssq[3];
        float mu  = sum * (1.f / D_MODEL);
        float var = sq  * (1.f / D_MODEL) - mu * mu;
        float rstd = rsqrtf(var + LN_EPS);
        const float4 gv = ((const float4*)gamma)[tid];
        const float4 bv = ((const float4*)beta)[tid];
        ushort4 o;
        o.x = f2bf((v.x - mu) * rstd * gv.x + bv.x);
        o.y = f2bf((v.y - mu) * rstd * gv.y + bv.y);
        o.z = f2bf((v.z - mu) * rstd * gv.z + bv.z);
        o.w = f2bf((v.w - mu) * rstd * gv.w + bv.w);
        ((ushort4*)(h + (size_t)row * D_MODEL))[tid] = o;
        return;
    }
    {
        int lane = threadIdx.x & 63;
        int c = (b - 3072) * 4 + (threadIdx.x >> 6);
        float e1 = __expf(-__expf(A_log[c * 64 + lane]));
        float wgt = Bp[c * 64 + lane] * Cp[c * 64 + lane];
        float d0 = Dp[c];
        #pragma unroll
        for (int d = 0; d < SKTAPS; ++d) {
            float s = wgt;
            s += __shfl_xor(s, 32);
            s += __shfl_xor(s, 16);
            s += __shfl_xor(s, 8);
            s += __shfl_xor(s, 4);
            s += __shfl_xor(s, 2);
            s += __shfl_xor(s, 1);
            if (lane == 0) kbuf[(size_t)d * INNER + c] = s + (d == 0 ? d0 : 0.f);
            wgt *= e1;
        }
    }
}

// ---------------- GEMM1: 64x128 tile, dbuf + counted vmcnt (T4), XCD-chunked ----
__global__ __launch_bounds__(256) void gemm1_kernel(
    const unsigned short* __restrict__ A,
    const unsigned short* __restrict__ Bt,
    const float* __restrict__ bias,
    unsigned short* __restrict__ C,
    int M, int N, int K) {
    constexpr int BM = 64, BN = 128, BK = 64;
    constexpr int FM = 2, FN = 4;
    __shared__ __align__(16) unsigned short As[2][BM * BK];
    __shared__ __align__(16) unsigned short Bs[2][BN * BK];
    const int t = threadIdx.x;
    const int lane = t & 63;
    const int wave = t >> 6;
    const int wm = wave >> 1, wn = wave & 1;
    const int bid = blockIdx.x;
    const int xcd = bid & 7, idx = bid >> 3;
    const int mi = ((xcd & 1) << 3) + (idx & 7);
    const int ni = (xcd >> 1) * 12 + (idx >> 3);
    const int m0 = mi * BM;
    const int n0 = ni * BN;
    f32x4 acc[FM][FN] = {};

    const int srow = t >> 3;
    const int schunk = t & 7;

    auto stage = [&](int buf, int k0) {   // 6 gload_lds per thread
        #pragma unroll
        for (int i = 0; i < BM / 32; ++i) {
            int r = i * 32 + srow;
            int js = schunk ^ (r & 7);
            gload_lds16(A + (size_t)(m0 + r) * K + k0 + js * 8,
                        ((char*)As[buf]) + i * 4096 + wave * 1024);
        }
        #pragma unroll
        for (int i = 0; i < BN / 32; ++i) {
            int r = i * 32 + srow;
            int js = schunk ^ (r & 7);
            gload_lds16(Bt + (size_t)(n0 + r) * K + k0 + js * 8,
                        ((char*)Bs[buf]) + i * 4096 + wave * 1024);
        }
    };
    auto compute = [&](int buf) {
        #pragma unroll
        for (int kt = 0; kt < 2; ++kt) {
            bf16x8 af[FM], bfr[FN];
            #pragma unroll
            for (int i = 0; i < FM; ++i) {
                int row = wm * (BM / 2) + i * 16 + (lane & 15);
                int chunk = (kt * 4 + (lane >> 4)) ^ (row & 7);
                af[i] = *(const bf16x8*)(((const char*)As[buf]) + row * 128 + chunk * 16);
            }
            #pragma unroll
            for (int j = 0; j < FN; ++j) {
                int row = wn * (BN / 2) + j * 16 + (lane & 15);
                int chunk = (kt * 4 + (lane >> 4)) ^ (row & 7);
                bfr[j] = *(const bf16x8*)(((const char*)Bs[buf]) + row * 128 + chunk * 16);
            }
            #pragma unroll
            for (int i = 0; i < FM; ++i)
                #pragma unroll
                for (int j = 0; j < FN; ++j)
                    acc[i][j] = __builtin_amdgcn_mfma_f32_16x16x32_bf16(
                        af[i], bfr[j], acc[i][j], 0, 0, 0);
        }
    };

    // prologue: tile 0 staged and drained
    stage(0, 0);
    asm volatile("s_waitcnt vmcnt(0)" ::: "memory");
    __builtin_amdgcn_s_barrier();
    int cur = 0;
    const int NT = K / BK;
    for (int tt = 0; tt + 1 < NT; ++tt) {
        stage(cur ^ 1, (tt + 1) * BK);            // 6 new loads in flight
        asm volatile("s_waitcnt vmcnt(6)" ::: "memory");  // tile-tt loads done
        __builtin_amdgcn_s_barrier();
        compute(cur);
        asm volatile("" ::: "memory");
        __builtin_amdgcn_s_barrier();             // buf free for restage
        cur ^= 1;
    }
    asm volatile("s_waitcnt vmcnt(0)" ::: "memory");
    __builtin_amdgcn_s_barrier();
    compute(cur);

    #pragma unroll
    for (int i = 0; i < FM; ++i) {
        #pragma unroll
        for (int j = 0; j < FN; ++j) {
            int col = n0 + wn * (BN / 2) + j * 16 + (lane & 15);
            float bv = bias[col];
            #pragma unroll
            for (int r = 0; r < 4; ++r) {
                int row = m0 + wm * (BM / 2) + i * 16 + (lane >> 4) * 4 + r;
                C[(size_t)row * N + col] = f2bf(acc[i][j][r] + bv);
            }
        }
    }
}

// ---------------- GEMM2: in-block split-K, dbuf + counted vmcnt, XCD-chunked ----
__global__ __launch_bounds__(512) void gemm2_kernel(
    const unsigned short* __restrict__ A,
    const unsigned short* __restrict__ Bt,
    const float* __restrict__ bias,
    const float* __restrict__ resid,
    float* __restrict__ out) {
    constexpr int N = D_MODEL, K = INNER, BK = 64, KH = K / 2;
    __shared__ __align__(16) unsigned short As[2][2][64 * 64];  // [buf][kz]
    __shared__ __align__(16) unsigned short Bs[2][2][64 * 64];
    const int t = threadIdx.x;
    const int lane = t & 63;
    const int wave = t >> 6;
    const int kz = wave >> 2;
    const int w2 = wave & 3;
    const int wm = w2 >> 1, wn = w2 & 1;
    const int bid = blockIdx.x;
    const int xcd = bid & 7, idx = bid >> 3;
    const int mi = ((xcd & 1) << 3) + (idx & 7);
    const int ni = (xcd >> 1) * 4 + (idx >> 3);
    const int m0 = mi * 64, n0 = ni * 64;
    f32x4 acc[2][2] = {};
    const int t4 = t & 255;
    const int srow = t4 >> 3, schunk = t4 & 7;
    const unsigned short* Abase = A + (size_t)kz * KH;
    const unsigned short* Bbase = Bt + (size_t)kz * KH;

    auto stage = [&](int buf, int k0) {   // 4 gload_lds per thread
        #pragma unroll
        for (int i = 0; i < 2; ++i) {
            int r = i * 32 + srow;
            int js = schunk ^ (r & 7);
            gload_lds16(Abase + (size_t)(m0 + r) * K + k0 + js * 8,
                        ((char*)As[buf][kz]) + i * 4096 + w2 * 1024);
            gload_lds16(Bbase + (size_t)(n0 + r) * K + k0 + js * 8,
                        ((char*)Bs[buf][kz]) + i * 4096 + w2 * 1024);
        }
    };
    auto compute = [&](int buf) {
        #pragma unroll
        for (int kt = 0; kt < 2; ++kt) {
            bf16x8 af[2], bfr[2];
            #pragma unroll
            for (int i = 0; i < 2; ++i) {
                int row = wm * 32 + i * 16 + (lane & 15);
                int chunk = (kt * 4 + (lane >> 4)) ^ (row & 7);
                af[i] = *(const bf16x8*)(((const char*)As[buf][kz]) + row * 128 + chunk * 16);
            }
            #pragma unroll
            for (int j = 0; j < 2; ++j) {
                int row = wn * 32 + j * 16 + (lane & 15);
                int chunk = (kt * 4 + (lane >> 4)) ^ (row & 7);
                bfr[j] = *(const bf16x8*)(((const char*)Bs[buf][kz]) + row * 128 + chunk * 16);
            }
            #pragma unroll
            for (int i = 0; i < 2; ++i)
                #pragma unroll
                for (int j = 0; j < 2; ++j)
                    acc[i][j] = __builtin_amdgcn_mfma_f32_16x16x32_bf16(
                        af[i], bfr[j], acc[i][j], 0, 0, 0);
        }
    };

    stage(0, 0);
    asm volatile("s_waitcnt vmcnt(0)" ::: "memory");
    __builtin_amdgcn_s_barrier();
    int cur = 0;
    constexpr int NT = KH / BK;
    for (int tt = 0; tt + 1 < NT; ++tt) {
        stage(cur ^ 1, (tt + 1) * BK);
        asm volatile("s_waitcnt vmcnt(4)" ::: "memory");
        __builtin_amdgcn_s_barrier();
        compute(cur);
        asm volatile("" ::: "memory");
        __builtin_amdgcn_s_barrier();
        cur ^= 1;
    }
    asm volatile("s_waitcnt vmcnt(0)" ::: "memory");
    __builtin_amdgcn_s_barrier();
    compute(cur);
    __syncthreads();   // full drain before LDS scratch reuse

    float* scratch = (float*)&As[0][0][0];
    if (kz == 1) {
        #pragma unroll
        for (int i = 0; i < 2; ++i)
            #pragma unroll
            for (int j = 0; j < 2; ++j)
                #pragma unroll
                for (int r = 0; r < 4; ++r)
                    scratch[(w2 * 64 + lane) * 17 + (i * 2 + j) * 4 + r] = acc[i][j][r];
    }
    __syncthreads();
    if (kz == 0) {
        #pragma unroll
        for (int i = 0; i < 2; ++i)
            #pragma unroll
            for (int j = 0; j < 2; ++j) {
                int col = n0 + wn * 32 + j * 16 + (lane & 15);
                float bv = bias[col];
                #pragma unroll
                for (int r = 0; r < 4; ++r) {
                    int row = m0 + wm * 32 + i * 16 + (lane >> 4) * 4 + r;
                    float val = acc[i][j][r]
                              + scratch[(w2 * 64 + lane) * 17 + (i * 2 + j) * 4 + r]
                              + bv + resid[(size_t)row * N + col];
                    out[(size_t)row * N + col] = val;
                }
            }
    }
}

// ---------------- fused: silu(conv3(u)) -> 32-tap causal conv -> gate ----------------
__global__ __launch_bounds__(256) void ssm_fused_kernel(
    const unsigned short* __restrict__ uvg,
    const float* __restrict__ conv_w, const float* __restrict__ conv_b,
    const float* __restrict__ kbuf,
    unsigned short* __restrict__ ybf) {
    int lane = threadIdx.x & 63;
    int wave = threadIdx.x >> 6;
    int c = (blockIdx.x & 31) * 64 + lane;
    int t0 = (blockIdx.x >> 5) * 64 + wave * 16;
    const unsigned short* up = uvg + c;
    const float* kc = kbuf + c;
    float cw0 = conv_w[c * 3 + 0];
    float cw1 = conv_w[c * 3 + 1];
    float cw2 = conv_w[c * 3 + 2];
    float cb  = conv_b[c];

    auto raw = [&](int tt) -> float {
        return (tt >= 0 && tt < LSEQ) ? bf2f(up[(size_t)tt * THREE_INNER]) : 0.f;
    };
    auto clean = [&](float rm1, float r0, float rp1) -> float {
        float a = fmaf(rp1, cw2, fmaf(r0, cw1, fmaf(rm1, cw0, cb)));
        return a * sigm(a);
    };

    float w[16];
    {
        float rm1 = raw(t0 - 1), r0 = raw(t0);
        #pragma unroll
        for (int j = 0; j < 16; ++j) {
            float rp1 = raw(t0 + j + 1);
            w[j] = clean(rm1, r0, rp1);
            rm1 = r0; r0 = rp1;
        }
    }
    float acc[16] = {};
    float q0 = raw(t0), q1 = raw(t0 - 1);
    #pragma unroll
    for (int d = 0; d < SKTAPS; ++d) {
        float kd = kc[(size_t)d * INNER];
        #pragma unroll
        for (int j = 0; j < 16; ++j) acc[j] = fmaf(kd, w[j], acc[j]);
        if (d < SKTAPS - 1) {
            float q2 = raw(t0 - 2 - d);
            float nc = (t0 - 1 - d >= 0) ? clean(q2, q1, q0) : 0.f;
            #pragma unroll
            for (int j = 15; j > 0; --j) w[j] = w[j - 1];
            w[0] = nc;
            q0 = q1; q1 = q2;
        }
    }
    #pragma unroll
    for (int j = 0; j < 16; ++j) {
        size_t tt = (size_t)(t0 + j);
        float v = bf2f(uvg[tt * THREE_INNER + INNER + c]);
        float g = bf2f(uvg[tt * THREE_INNER + 2 * INNER + c]);
        float o = acc[j] * sigm(g) + v * sigm(v);
        ybf[tt * INNER + c] = f2bf(o);
    }
}

extern "C" void kernel_launch(void* const* d_in, const int* in_sizes, int n_in,
                              void* d_out, int out_size, void* d_ws, size_t ws_size,
                              hipStream_t stream) {
    const float* x       = (const float*)d_in[0];
    const float* gamma   = (const float*)d_in[1];
    const float* beta    = (const float*)d_in[2];
    const float* in_w    = (const float*)d_in[3];
    const float* in_b    = (const float*)d_in[4];
    const float* conv_w  = (const float*)d_in[5];
    const float* conv_b  = (const float*)d_in[6];
    const float* A_log   = (const float*)d_in[7];
    const float* B_p     = (const float*)d_in[8];
    const float* C_p     = (const float*)d_in[9];
    const float* D_p     = (const float*)d_in[10];
    const float* out_w   = (const float*)d_in[11];
    const float* out_b   = (const float*)d_in[12];
    float* out = (float*)d_out;

    char* ws = (char*)d_ws;
    unsigned short* h      = (unsigned short*)ws;  ws += (size_t)LSEQ * D_MODEL * 2;
    unsigned short* uvg    = (unsigned short*)ws;  ws += (size_t)LSEQ * THREE_INNER * 2;
    unsigned short* ybf    = (unsigned short*)ws;  ws += (size_t)LSEQ * INNER * 2;
    float*          kbuf   = (float*)ws;           ws += (size_t)SKTAPS * INNER * 4;
    unsigned short* in_wt  = (unsigned short*)ws;  ws += (size_t)THREE_INNER * D_MODEL * 2;
    unsigned short* out_wt = (unsigned short*)ws;  ws += (size_t)D_MODEL * INNER * 2;

    prep_kernel<<<3584, 256, 0, stream>>>(in_w, in_wt, out_w, out_wt,
                                          x, gamma, beta, h,
                                          A_log, B_p, C_p, D_p, kbuf);

    gemm1_kernel<<<768, 256, 0, stream>>>(h, in_wt, in_b, uvg,
                                          LSEQ, THREE_INNER, D_MODEL);

    ssm_fused_kernel<<<(LSEQ / 64) * 32, 256, 0, stream>>>(uvg, conv_w, conv_b, kbuf, ybf);

    gemm2_kernel<<<256, 512, 0, stream>>>(ybf, out_wt, out_b, x, out);
}